// Round 11
// baseline (272.938 us; speedup 1.0000x reference)
//
#include <hip/hip_runtime.h>
#include <math.h>

#define NB 32
#define LL 512
#define PP 256
#define HH 8
#define EE 128
#define DD 1024

typedef __attribute__((ext_vector_type(4))) float f32x4;
typedef __attribute__((ext_vector_type(8))) short short8;

__device__ __forceinline__ float gelu_f(float v) {
    return 0.5f * v * (1.0f + erff(v * 0.70710678118654752f));
}
__device__ __forceinline__ float rcp_f(float v) {
    float r; asm("v_rcp_f32 %0, %1" : "=v"(r) : "v"(v)); return r;
}
__device__ __forceinline__ unsigned short bf16_rne(float v) {
    unsigned u = __float_as_uint(v);
    unsigned r = u + 0x7FFFu + ((u >> 16) & 1u);
    return (unsigned short)(r >> 16);
}
__device__ __forceinline__ float bf2f(short s) {
    return __uint_as_float(((unsigned)(unsigned short)s) << 16);
}

// ---------------- kpack: W (128x128 fp32) -> bf16 hi/lo in MFMA B-fragment order
__global__ __launch_bounds__(256) void kpack(const float* __restrict__ W1,
                                             const float* __restrict__ W3,
                                             unsigned short* __restrict__ W1h,
                                             unsigned short* __restrict__ W1l,
                                             unsigned short* __restrict__ W3h,
                                             unsigned short* __restrict__ W3l) {
    const float* W = blockIdx.x ? W3 : W1;
    unsigned short* Ph = blockIdx.x ? W3h : W1h;
    unsigned short* Pl = blockIdx.x ? W3l : W1l;
    for (int i = threadIdx.x; i < 16384; i += 256) {
        int oct = i >> 10, col = (i >> 3) & 127, j = i & 7;
        float v = W[(oct * 8 + j) * 128 + col];
        unsigned short hb = bf16_rne(v);
        float hf = __uint_as_float((unsigned)hb << 16);
        Ph[i] = hb;
        Pl[i] = bf16_rne(v - hf);
    }
}

// ---------------- K0: pack mask to bits (row-major + col-major) + no-edge flags
__global__ __launch_bounds__(256) void k0_bits(const float* __restrict__ adj,
                                               unsigned* __restrict__ bits,
                                               unsigned* __restrict__ bitsT,
                                               unsigned* __restrict__ flags) {
    __shared__ unsigned lbits[64][8];
    int n  = blockIdx.x >> 3;
    int l0 = (blockIdx.x & 7) * 64;
    int lane = threadIdx.x & 63;
    int wv   = threadIdx.x >> 6;
    for (int r = wv; r < 64; r += 4) {
        int l = l0 + r;
        const float* row = adj + ((size_t)n * LL + l) * PP;
        int cnt = 0;
        for (int c = 0; c < 4; ++c) {
            float v = row[c * 64 + lane];
            unsigned long long b = __ballot(v != 0.0f);
            if (lane == 0) {
                lbits[r][c * 2]     = (unsigned)b;
                lbits[r][c * 2 + 1] = (unsigned)(b >> 32);
                cnt += __popcll(b);
            }
        }
        if (lane == 0) {
            flags[n * LL + l] = (cnt == 0) ? 1u : 0u;
            for (int w = 0; w < 8; ++w)
                bits[((size_t)n * LL + l) * 8 + w] = lbits[r][w];
        }
    }
    __syncthreads();
    int p = threadIdx.x;
    unsigned w0 = 0, w1 = 0;
    int wp = p >> 5, bp = p & 31;
    for (int j = 0; j < 32; ++j) {
        w0 |= ((lbits[j][wp] >> bp) & 1u) << j;
        w1 |= ((lbits[j + 32][wp] >> bp) & 1u) << j;
    }
    bitsT[((size_t)n * PP + p) * 16 + (l0 >> 5)]     = w0;
    bitsT[((size_t)n * PP + p) * 16 + (l0 >> 5) + 1] = w1;
}

// ---------------- gemm1b: xh = x@W1+b1 in-register; outputs k-packed bf16 xhb + per-row (xv,an) partials
__global__ __launch_bounds__(256) void gemm1b(const float* __restrict__ A,
                                              const unsigned short* __restrict__ Bhi,
                                              const unsigned short* __restrict__ Blo,
                                              const float* __restrict__ bias,
                                              const float* __restrict__ W2,
                                              const float* __restrict__ W4,
                                              unsigned short* __restrict__ xhb,
                                              float* __restrict__ xvan) {
    __shared__ __align__(16) char buf[65536];   // As fp32 (64 KB) -> tbuf bf16 (32 KB)
    float* As = (float*)buf;
    unsigned short* tbuf = (unsigned short*)buf;
    int tid = threadIdx.x, lane = tid & 63, w = tid >> 6;
    int b = blockIdx.x;
    size_t blockRow0 = (size_t)b * 128;
    int rl = lane & 15, g = lane >> 4;
    {   // coalesced stage of A tile (swizzled rows)
        const f32x4* Ag = (const f32x4*)(A + blockRow0 * 128);
        #pragma unroll
        for (int i = 0; i < 16; ++i) {
            int idx = i * 256 + tid;
            int row = idx >> 5, c4 = idx & 31;
            f32x4 v = Ag[idx];
            *(f32x4*)((char*)As + ((row * 512 + c4 * 16) ^ ((row & 7) << 5))) = v;
        }
    }
    __syncthreads();

    f32x4 acc[2][8];
    #pragma unroll
    for (int t = 0; t < 2; ++t)
        #pragma unroll
        for (int nt = 0; nt < 8; ++nt) acc[t][nt] = (f32x4){0.f, 0.f, 0.f, 0.f};

    #pragma unroll
    for (int kc = 0; kc < 4; ++kc) {
        short8 ah[2], al[2];
        #pragma unroll
        for (int t = 0; t < 2; ++t) {
            int arow = w * 32 + t * 16 + rl;
            int cb = (kc * 32 + g * 8) * 4;
            int sw = (arow & 7) << 5;
            f32x4 a0 = *(const f32x4*)((char*)As + ((arow * 512 + cb) ^ sw));
            f32x4 a1 = *(const f32x4*)((char*)As + ((arow * 512 + cb + 16) ^ sw));
            float av[8] = {a0.x, a0.y, a0.z, a0.w, a1.x, a1.y, a1.z, a1.w};
            #pragma unroll
            for (int j = 0; j < 8; ++j) {
                unsigned short hb = bf16_rne(av[j]);
                float hf = __uint_as_float((unsigned)hb << 16);
                ah[t][j] = (short)hb;
                al[t][j] = (short)bf16_rne(av[j] - hf);
            }
        }
        #pragma unroll
        for (int nt = 0; nt < 8; ++nt) {
            int oct = kc * 4 + g, col = nt * 16 + rl;
            short8 bh = *(const short8*)(Bhi + ((size_t)(oct * 128 + col)) * 8);
            short8 bl = *(const short8*)(Blo + ((size_t)(oct * 128 + col)) * 8);
            #pragma unroll
            for (int t = 0; t < 2; ++t) {
                acc[t][nt] = __builtin_amdgcn_mfma_f32_16x16x32_bf16(ah[t], bh, acc[t][nt], 0, 0, 0);
                acc[t][nt] = __builtin_amdgcn_mfma_f32_16x16x32_bf16(ah[t], bl, acc[t][nt], 0, 0, 0);
                acc[t][nt] = __builtin_amdgcn_mfma_f32_16x16x32_bf16(al[t], bh, acc[t][nt], 0, 0, 0);
            }
        }
    }
    __syncthreads();   // done with As; reuse buf as tbuf

    float xv_p[2][4] = {{0.f,0.f,0.f,0.f},{0.f,0.f,0.f,0.f}};
    float an_p[2][4] = {{0.f,0.f,0.f,0.f},{0.f,0.f,0.f,0.f}};
    #pragma unroll
    for (int nt = 0; nt < 8; ++nt) {
        int col = nt * 16 + rl;
        float bv = bias[col], w2v = W2[col], w4v = W4[128 + col];
        #pragma unroll
        for (int t = 0; t < 2; ++t) {
            float v0 = acc[t][nt][0] + bv;
            float v1 = acc[t][nt][1] + bv;
            float v2 = acc[t][nt][2] + bv;
            float v3 = acc[t][nt][3] + bv;
            xv_p[t][0] += gelu_f(v0) * w2v;  an_p[t][0] += gelu_f(v0) * w4v;
            xv_p[t][1] += gelu_f(v1) * w2v;  an_p[t][1] += gelu_f(v1) * w4v;
            xv_p[t][2] += gelu_f(v2) * w2v;  an_p[t][2] += gelu_f(v2) * w4v;
            xv_p[t][3] += gelu_f(v3) * w2v;  an_p[t][3] += gelu_f(v3) * w4v;
            int row_loc = w * 32 + t * 16 + g * 4;
            int byte = (col * 256 + row_loc * 2) ^ ((col & 7) << 4);
            *(ushort4*)((char*)tbuf + byte) =
                make_ushort4(bf16_rne(v0), bf16_rne(v1), bf16_rne(v2), bf16_rne(v3));
        }
    }
    #pragma unroll
    for (int t = 0; t < 2; ++t)
        #pragma unroll
        for (int r = 0; r < 4; ++r) {
            float a = xv_p[t][r], c = an_p[t][r];
            a += __shfl_xor(a, 1); a += __shfl_xor(a, 2); a += __shfl_xor(a, 4); a += __shfl_xor(a, 8);
            c += __shfl_xor(c, 1); c += __shfl_xor(c, 2); c += __shfl_xor(c, 4); c += __shfl_xor(c, 8);
            if (rl == 0) {
                size_t row = blockRow0 + w * 32 + t * 16 + g * 4 + r;
                *(float2*)(xvan + row * 2) = make_float2(a, c);
            }
        }
    __syncthreads();
    // tbuf -> global k-packed bf16: xhb[(n*8+h)][ (kg0+kg_loc)*128 + e ][8 lpos]
    int n = b >> 5, kg0 = (b & 31) * 2;
    #pragma unroll
    for (int rep = 0; rep < 8; ++rep) {
        int id = rep * 256 + tid;
        int h = id >> 8, kg_loc = (id >> 7) & 1, e = id & 127;
        short8 v;
        #pragma unroll
        for (int lpos = 0; lpos < 8; ++lpos) {
            int byte = (e * 256 + kg_loc * 128 + lpos * 16 + h * 2) ^ ((e & 7) << 4);
            v[lpos] = *(const short*)((char*)tbuf + byte);
        }
        *(short8*)(xhb + ((size_t)(n * 8 + h)) * 65536 + (size_t)((kg0 + kg_loc) * 128 + e) * 8) = v;
    }
}

// ---------------- k1c: softmax over heads from (xv,an) partials -> sb bf16, eu
__global__ __launch_bounds__(256) void k1c_softmax(const float* __restrict__ xvan,
                                                   unsigned short* __restrict__ sb,
                                                   float* __restrict__ eu) {
    int gidx = blockIdx.x * 256 + threadIdx.x;   // (n*512+l), 16384 total
    int n = gidx >> 9, l = gidx & 511;
    float b16[16];
    #pragma unroll
    for (int q = 0; q < 4; ++q) {
        f32x4 v = *(const f32x4*)(xvan + (size_t)gidx * 16 + q * 4);
        b16[q * 4 + 0] = v.x; b16[q * 4 + 1] = v.y; b16[q * 4 + 2] = v.z; b16[q * 4 + 3] = v.w;
    }
    float xv[8], an[8];
    #pragma unroll
    for (int h = 0; h < 8; ++h) { xv[h] = b16[h * 2]; an[h] = b16[h * 2 + 1]; }
    float mx = xv[0];
    #pragma unroll
    for (int h = 1; h < 8; ++h) mx = fmaxf(mx, xv[h]);
    float ex[8], ssum = 0.f;
    #pragma unroll
    for (int h = 0; h < 8; ++h) { ex[h] = expf(xv[h] - mx); ssum += ex[h]; }
    float inv = 1.0f / ssum;
    #pragma unroll
    for (int h = 0; h < 8; ++h)
        sb[((size_t)(n * 8 + h)) * 512 + l] = bf16_rne(ex[h] * inv);
    float mxa = an[0];
    #pragma unroll
    for (int h = 1; h < 8; ++h) mxa = fmaxf(mxa, an[h]);
    f32x4 e0, e1;
    #pragma unroll
    for (int h = 0; h < 4; ++h) e0[h] = expf(an[h] - mxa);
    #pragma unroll
    for (int h = 0; h < 4; ++h) e1[h] = expf(an[4 + h] - mxa);
    float* ep = eu + (size_t)gidx * 8;
    *(f32x4*)ep = e0;
    *(f32x4*)(ep + 4) = e1;
}

// ---------------- k2_mfma: heg = gelu(A' @ xh); xhb bf16 k-packed input; 1024 threads
__global__ __launch_bounds__(1024) void k2_mfma(const unsigned short* __restrict__ xhb,
                                                const unsigned short* __restrict__ s_in,
                                                const unsigned* __restrict__ bitsT,
                                                float* __restrict__ heg) {
    __shared__ __align__(16) unsigned short kpk[65536];    // 128 KB
    __shared__ unsigned bT_s[16 * 256];                    // [kt][p], 16 KB
    __shared__ __align__(16) unsigned short smb_s[512];    // bf16(s), 1 KB
    int bh = blockIdx.x;
    int n = bh >> 3;
    int tid = threadIdx.x, lane = tid & 63, w = tid >> 6;

    {
        int p = tid >> 2, q = tid & 3;
        uint4 wds = *(const uint4*)(bitsT + ((size_t)(n * 256 + p)) * 16 + q * 4);
        bT_s[(q * 4 + 0) * 256 + p] = wds.x;
        bT_s[(q * 4 + 1) * 256 + p] = wds.y;
        bT_s[(q * 4 + 2) * 256 + p] = wds.z;
        bT_s[(q * 4 + 3) * 256 + p] = wds.w;
    }
    if (tid < 512) smb_s[tid] = s_in[(size_t)bh * 512 + tid];
    {
        const unsigned short* xb = xhb + (size_t)bh * 65536;
        #pragma unroll
        for (int rep = 0; rep < 8; ++rep) {
            int idx = rep * 1024 + tid;
            *(short8*)&kpk[idx * 8] = *(const short8*)(xb + (size_t)idx * 8);
        }
    }
    __syncthreads();

    int rl = lane & 15, g = lane >> 4;
    int wm = w & 7, wn = w >> 3;
    f32x4 acc[2][4];
    #pragma unroll
    for (int i = 0; i < 2; ++i)
        #pragma unroll
        for (int nt = 0; nt < 4; ++nt) acc[i][nt] = (f32x4){0.f, 0.f, 0.f, 0.f};

    for (int kt = 0; kt < 16; ++kt) {
        short8 sv = *(const short8*)&smb_s[kt * 32 + g * 8];
        short8 bfr[4];
        #pragma unroll
        for (int nt = 0; nt < 4; ++nt)
            bfr[nt] = *(const short8*)&kpk[(((kt * 4 + g) << 7) + wn * 64 + nt * 16 + rl) * 8];
        #pragma unroll
        for (int i = 0; i < 2; ++i) {
            unsigned word = bT_s[kt * 256 + (wm * 2 + i) * 16 + rl];
            unsigned byte = (word >> (g * 8)) & 255u;
            short8 af;
            #pragma unroll
            for (int j = 0; j < 8; ++j)
                af[j] = ((byte >> j) & 1u) ? sv[j] : (short)0x3E00;
            #pragma unroll
            for (int nt = 0; nt < 4; ++nt)
                acc[i][nt] = __builtin_amdgcn_mfma_f32_16x16x32_bf16(af, bfr[nt], acc[i][nt], 0, 0, 0);
        }
    }

    float* ob = heg + (size_t)bh * (PP * EE);
    #pragma unroll
    for (int i = 0; i < 2; ++i)
        #pragma unroll
        for (int nt = 0; nt < 4; ++nt) {
            int e = wn * 64 + nt * 16 + rl;
            #pragma unroll
            for (int r = 0; r < 4; ++r) {
                int p = (wm * 2 + i) * 16 + g * 4 + r;
                ob[(size_t)p * 128 + e] = gelu_f(acc[i][nt][r]);
            }
        }
}

// ---------------- gemm3: he = heg@W3+b3 in-register; fused ev + heT bf16 transpose output
__global__ __launch_bounds__(256) void gemm3(const float* __restrict__ A,
                                             const unsigned short* __restrict__ Bhi,
                                             const unsigned short* __restrict__ Blo,
                                             const float* __restrict__ bias,
                                             const float* __restrict__ W4,
                                             unsigned short* __restrict__ heT,
                                             float* __restrict__ ev) {
    __shared__ __align__(16) char buf[65536];   // As fp32 (64 KB) -> tbuf bf16 (32 KB)
    __shared__ float rs_ae[128];
    float* As = (float*)buf;
    unsigned short* tbuf = (unsigned short*)buf;
    int tid = threadIdx.x, lane = tid & 63, w = tid >> 6;
    size_t blockRow0 = (size_t)blockIdx.x * 128;
    int rl = lane & 15, g = lane >> 4;
    {
        const f32x4* Ag = (const f32x4*)(A + blockRow0 * 128);
        #pragma unroll
        for (int i = 0; i < 16; ++i) {
            int idx = i * 256 + tid;
            int row = idx >> 5, c4 = idx & 31;
            f32x4 v = Ag[idx];
            *(f32x4*)((char*)As + ((row * 512 + c4 * 16) ^ ((row & 7) << 5))) = v;
        }
    }
    __syncthreads();

    f32x4 acc[2][8];
    #pragma unroll
    for (int t = 0; t < 2; ++t)
        #pragma unroll
        for (int nt = 0; nt < 8; ++nt) acc[t][nt] = (f32x4){0.f, 0.f, 0.f, 0.f};

    #pragma unroll
    for (int kc = 0; kc < 4; ++kc) {
        short8 ah[2], al[2];
        #pragma unroll
        for (int t = 0; t < 2; ++t) {
            int arow = w * 32 + t * 16 + rl;
            int cb = (kc * 32 + g * 8) * 4;
            int sw = (arow & 7) << 5;
            f32x4 a0 = *(const f32x4*)((char*)As + ((arow * 512 + cb) ^ sw));
            f32x4 a1 = *(const f32x4*)((char*)As + ((arow * 512 + cb + 16) ^ sw));
            float av[8] = {a0.x, a0.y, a0.z, a0.w, a1.x, a1.y, a1.z, a1.w};
            #pragma unroll
            for (int j = 0; j < 8; ++j) {
                unsigned short hb = bf16_rne(av[j]);
                float hf = __uint_as_float((unsigned)hb << 16);
                ah[t][j] = (short)hb;
                al[t][j] = (short)bf16_rne(av[j] - hf);
            }
        }
        #pragma unroll
        for (int nt = 0; nt < 8; ++nt) {
            int oct = kc * 4 + g, col = nt * 16 + rl;
            short8 bh = *(const short8*)(Bhi + ((size_t)(oct * 128 + col)) * 8);
            short8 bl = *(const short8*)(Blo + ((size_t)(oct * 128 + col)) * 8);
            #pragma unroll
            for (int t = 0; t < 2; ++t) {
                acc[t][nt] = __builtin_amdgcn_mfma_f32_16x16x32_bf16(ah[t], bh, acc[t][nt], 0, 0, 0);
                acc[t][nt] = __builtin_amdgcn_mfma_f32_16x16x32_bf16(ah[t], bl, acc[t][nt], 0, 0, 0);
                acc[t][nt] = __builtin_amdgcn_mfma_f32_16x16x32_bf16(al[t], bh, acc[t][nt], 0, 0, 0);
            }
        }
    }
    __syncthreads();   // done with As; reuse buf as tbuf

    float ae_p[2][4] = {{0.f,0.f,0.f,0.f},{0.f,0.f,0.f,0.f}};
    #pragma unroll
    for (int nt = 0; nt < 8; ++nt) {
        int col = nt * 16 + rl;
        float bv = bias[col], w4v = W4[col];
        #pragma unroll
        for (int t = 0; t < 2; ++t) {
            float v0 = acc[t][nt][0] + bv;
            float v1 = acc[t][nt][1] + bv;
            float v2 = acc[t][nt][2] + bv;
            float v3 = acc[t][nt][3] + bv;
            ae_p[t][0] += gelu_f(v0) * w4v;
            ae_p[t][1] += gelu_f(v1) * w4v;
            ae_p[t][2] += gelu_f(v2) * w4v;
            ae_p[t][3] += gelu_f(v3) * w4v;
            int row_loc = w * 32 + t * 16 + g * 4;
            int byte = (col * 256 + row_loc * 2) ^ ((col & 7) << 4);
            *(ushort4*)((char*)tbuf + byte) =
                make_ushort4(bf16_rne(v0), bf16_rne(v1), bf16_rne(v2), bf16_rne(v3));
        }
    }
    #pragma unroll
    for (int t = 0; t < 2; ++t)
        #pragma unroll
        for (int r = 0; r < 4; ++r) {
            float a = ae_p[t][r];
            a += __shfl_xor(a, 1); a += __shfl_xor(a, 2); a += __shfl_xor(a, 4); a += __shfl_xor(a, 8);
            if (rl == 0) rs_ae[w * 32 + t * 16 + g * 4 + r] = a;
        }
    __syncthreads();
    int bh2 = blockIdx.x >> 1, p0 = (blockIdx.x & 1) * 128;
    #pragma unroll
    for (int rep = 0; rep < 8; ++rep) {
        int id = rep * 256 + tid;
        int e = id >> 4, j = id & 15;
        int byte = (e * 256 + j * 16) ^ ((e & 7) << 4);
        short8 v = *(const short8*)((char*)tbuf + byte);
        *(short8*)(heT + (size_t)bh2 * 32768 + (size_t)e * 256 + p0 + j * 8) = v;
    }
    if (tid < 128) {
        int row = blockIdx.x * 128 + tid;
        int n = row >> 11, h = (row >> 8) & 7, p = row & 255;
        ev[((size_t)(n * 256 + p)) * 8 + h] = expf(rs_ae[tid]);
    }
}

// ---------------- k4_dense: rdm[n][l][p] = bit ? 1/den : 0  (bf16, h-shared)
__global__ __launch_bounds__(256) void k4_dense(const float* __restrict__ eu,
                                                const float* __restrict__ ev,
                                                const unsigned* __restrict__ bits,
                                                unsigned short* __restrict__ rdm) {
    __shared__ float ev_t[256][8];
    int b = blockIdx.x;
    int n = b >> 3, l0 = (b & 7) * 64;
    int tid = threadIdx.x;
    {
        const f32x4* src = (const f32x4*)(ev + (size_t)n * 2048);
        f32x4* dst = (f32x4*)&ev_t[0][0];
        dst[tid] = src[tid];
        dst[tid + 256] = src[tid + 256];
    }
    __syncthreads();
    int l = l0 + (tid >> 2), pq = tid & 3;
    size_t rowg = (size_t)n * 512 + l;
    f32x4 ea = *(const f32x4*)(eu + rowg * 8);
    f32x4 eb = *(const f32x4*)(eu + rowg * 8 + 4);
    unsigned w0 = bits[rowg * 8 + pq * 2], w1 = bits[rowg * 8 + pq * 2 + 1];
    for (int c = 0; c < 8; ++c) {
        short8 o8;
        #pragma unroll
        for (int k = 0; k < 8; ++k) {
            int pl = c * 8 + k;
            int p = pq * 64 + pl;
            f32x4 va = *(const f32x4*)&ev_t[p][0];
            f32x4 vb = *(const f32x4*)&ev_t[p][4];
            float den = ea.x * va.x + ea.y * va.y + ea.z * va.z + ea.w * va.w
                      + eb.x * vb.x + eb.y * vb.y + eb.z * vb.z + eb.w * vb.w;
            unsigned bit = (pl < 32) ? ((w0 >> pl) & 1u) : ((w1 >> (pl - 32)) & 1u);
            float r = bit ? rcp_f(den) : 0.0f;
            o8[k] = (short)bf16_rne(r);
        }
        *(short8*)(rdm + rowg * 256 + pq * 64 + c * 8) = o8;
    }
}

// ---------------- k5_mfma: x_nodes = 0.125*colsum(he) + A @ he; 1024 threads (16 waves)
__global__ __launch_bounds__(1024) void k5_mfma(const unsigned short* __restrict__ heT,
                                                const unsigned short* __restrict__ rdm,
                                                const float* __restrict__ eu,
                                                const float* __restrict__ ev,
                                                const unsigned* __restrict__ flags,
                                                const float* __restrict__ x,
                                                float* __restrict__ out) {
    __shared__ __align__(16) unsigned short heT_s[128 * 256];  // swizzled [e][p], 64 KB
    __shared__ __align__(16) unsigned short A_s[64 * 256];     // swizzled [l_loc][p], 32 KB
    __shared__ float evh_s[256];
    __shared__ float euh_s[64];
    __shared__ float cs_s[128];
    __shared__ float csr_s[4][128];
    __shared__ unsigned flg_s[64];

    int bid = blockIdx.x;
    int xcd = bid & 7, slot = bid >> 3;          // group 8 heads of same n per XCD (rdm L2 reuse)
    int n = xcd * 4 + (slot & 3), h = slot >> 2;
    int bh = n * 8 + h;
    int tid = threadIdx.x, lane = tid & 63, w = tid >> 6;

    const unsigned short* hb = heT + (size_t)bh * 32768;
    #pragma unroll
    for (int i = 0; i < 4; ++i) {
        int id = tid + i * 1024;
        int e = id >> 5, jj = id & 31;
        short8 v = *(const short8*)(hb + e * 256 + jj * 8);
        *(short8*)((char*)heT_s + ((e * 512 + jj * 16) ^ ((e & 7) << 4))) = v;
    }
    if (tid < 256) evh_s[tid] = ev[((size_t)(n * 256 + tid)) * 8 + h];
    __syncthreads();
    if (tid < 512) {
        int e = tid & 127, q = tid >> 7;
        float a = 0.f;
        #pragma unroll
        for (int j = 0; j < 8; ++j) {
            int byte = (e * 512 + (q * 64 + j * 8) * 2) ^ ((e & 7) << 4);
            short8 v = *(const short8*)((char*)heT_s + byte);
            #pragma unroll
            for (int k = 0; k < 8; ++k) a += bf2f(v[k]);
        }
        csr_s[q][e] = a;
    }
    __syncthreads();
    if (tid < 128) cs_s[tid] = 0.125f * (csr_s[0][tid] + csr_s[1][tid] + csr_s[2][tid] + csr_s[3][tid]);

    int rl = lane & 15, g = lane >> 4;
    int wm = w & 3, wn = w >> 2;       // 4 mt x 4 e-groups (2 nt each)
    int swz = (rl & 7) << 4;

    for (int lt = 0; lt < 8; ++lt) {
        int l0 = lt * 64;
        if (tid < 64) {
            euh_s[tid] = eu[((size_t)(n * 512 + l0 + tid)) * 8 + h];
            flg_s[tid] = flags[n * 512 + l0 + tid];
        }
        __syncthreads();
        {
            int l_loc = tid >> 4, p8 = (tid & 15) * 16;
            float euh = euh_s[l_loc];
            const unsigned short* rp = rdm + ((size_t)(n * 512 + l0 + l_loc)) * 256 + p8;
            #pragma unroll
            for (int c = 0; c < 2; ++c) {
                short8 rv = *(const short8*)(rp + c * 8);
                short8 o8;
                #pragma unroll
                for (int k = 0; k < 8; ++k) {
                    unsigned u = (unsigned)(unsigned short)rv[k];
                    float rf = __uint_as_float(u << 16);
                    float m125 = (u != 0u) ? -0.125f : 0.0f;
                    float a = fmaf(euh * evh_s[p8 + c * 8 + k], rf, m125);
                    o8[k] = (short)bf16_rne(a);
                }
                *(short8*)((char*)A_s + ((l_loc * 512 + (p8 + c * 8) * 2) ^ ((l_loc & 7) << 4))) = o8;
            }
        }
        __syncthreads();
        f32x4 acc[2];
        acc[0] = (f32x4){0.f, 0.f, 0.f, 0.f};
        acc[1] = (f32x4){0.f, 0.f, 0.f, 0.f};
        #pragma unroll
        for (int kt = 0; kt < 8; ++kt) {
            int arow = wm * 16 + rl;
            short8 af = *(const short8*)((char*)A_s + ((arow * 512 + kt * 64 + g * 16) ^ swz));
            short8 b0, b1;
            {
                int e0 = wn * 32 + rl;
                int e1 = wn * 32 + 16 + rl;
                b0 = *(const short8*)((char*)heT_s + ((e0 * 512 + kt * 64 + g * 16) ^ swz));
                b1 = *(const short8*)((char*)heT_s + ((e1 * 512 + kt * 64 + g * 16) ^ swz));
            }
            acc[0] = __builtin_amdgcn_mfma_f32_16x16x32_bf16(af, b0, acc[0], 0, 0, 0);
            acc[1] = __builtin_amdgcn_mfma_f32_16x16x32_bf16(af, b1, acc[1], 0, 0, 0);
        }
        #pragma unroll
        for (int j = 0; j < 2; ++j) {
            int e = wn * 32 + j * 16 + rl;
            float csv = cs_s[e];
            #pragma unroll
            for (int r = 0; r < 4; ++r) {
                int row = wm * 16 + g * 4 + r;
                int l = l0 + row;
                size_t addr = ((size_t)(n * 512 + l)) * 1024 + h * 128 + e;
                if (flg_s[row]) {
                    out[addr] = x[addr];
                } else {
                    out[addr] = gelu_f(acc[j][r] + csv);
                }
            }
        }
        __syncthreads();
    }
}

extern "C" void kernel_launch(void* const* d_in, const int* in_sizes, int n_in,
                              void* d_out, int out_size, void* d_ws, size_t ws_size,
                              hipStream_t stream) {
    (void)in_sizes; (void)n_in; (void)out_size; (void)ws_size;
    const float* x   = (const float*)d_in[0];
    const float* adj = (const float*)d_in[1];
    const float* W1  = (const float*)d_in[2];
    const float* b1  = (const float*)d_in[3];
    const float* W2  = (const float*)d_in[4];
    const float* W3  = (const float*)d_in[6];
    const float* b3  = (const float*)d_in[7];
    const float* W4  = (const float*)d_in[8];
    float* out = (float*)d_out;

    char* ws = (char*)d_ws;
    size_t off = 0;
    auto alloc = [&](size_t bytes) -> void* {
        void* p = ws + off;
        off += (bytes + 255) & ~(size_t)255;
        return p;
    };
    unsigned short* xhb = (unsigned short*)alloc((size_t)NB * HH * 65536 * 2);   // 33.5 MB bf16 k-packed
    float* xvan = (float*)alloc((size_t)NB * LL * HH * 2 * 4);                   // 1 MB per-row partials
    unsigned short* sb  = (unsigned short*)alloc((size_t)NB * HH * LL * 2);      // bf16 s
    float* eu   = (float*)alloc((size_t)NB * LL * HH * 4);
    float* ev   = (float*)alloc((size_t)NB * PP * HH * 4);
    float* heg  = (float*)alloc((size_t)NB * HH * PP * EE * 4);                  // 33.5 MB
    unsigned short* heT = (unsigned short*)alloc((size_t)NB * HH * EE * PP * 2); // 16.8 MB [(n,h)][e][p]
    unsigned short* rdm = (unsigned short*)alloc((size_t)NB * LL * PP * 2);      // 8.4 MB [n][l][p]
    unsigned* bits  = (unsigned*)alloc((size_t)NB * LL * 8 * 4);
    unsigned* bitsT = (unsigned*)alloc((size_t)NB * PP * 16 * 4);
    unsigned* flags = (unsigned*)alloc((size_t)NB * LL * 4);
    unsigned short* W1h = (unsigned short*)alloc(16384 * 2);
    unsigned short* W1l = (unsigned short*)alloc(16384 * 2);
    unsigned short* W3h = (unsigned short*)alloc(16384 * 2);
    unsigned short* W3l = (unsigned short*)alloc(16384 * 2);

    hipLaunchKernelGGL(kpack, dim3(2), dim3(256), 0, stream, W1, W3, W1h, W1l, W3h, W3l);
    hipLaunchKernelGGL(k0_bits, dim3(NB * 8), dim3(256), 0, stream, adj, bits, bitsT, flags);
    hipLaunchKernelGGL(gemm1b, dim3(1024), dim3(256), 0, stream, x, W1h, W1l, b1, W2, W4, xhb, xvan);
    hipLaunchKernelGGL(k1c_softmax, dim3(64), dim3(256), 0, stream, xvan, sb, eu);
    hipLaunchKernelGGL(k2_mfma, dim3(NB * HH), dim3(1024), 0, stream, xhb, sb, bitsT, heg);
    hipLaunchKernelGGL(gemm3, dim3(512), dim3(256), 0, stream, heg, W3h, W3l, b3, W4, heT, ev);
    hipLaunchKernelGGL(k4_dense, dim3(NB * 8), dim3(256), 0, stream, eu, ev, bits, rdm);
    hipLaunchKernelGGL(k5_mfma, dim3(NB * HH), dim3(1024), 0, stream, heT, rdm, eu, ev, flags, x, out);
}

// Round 12
// 216.388 us; speedup vs baseline: 1.2613x; 1.2613x over previous
//
#include <hip/hip_runtime.h>
#include <math.h>

#define NB 32
#define LL 512
#define PP 256
#define HH 8
#define EE 128
#define DD 1024

typedef __attribute__((ext_vector_type(4))) float f32x4;
typedef __attribute__((ext_vector_type(8))) short short8;

__device__ __forceinline__ float gelu_f(float v) {
    return 0.5f * v * (1.0f + erff(v * 0.70710678118654752f));
}
__device__ __forceinline__ float rcp_f(float v) {
    float r; asm("v_rcp_f32 %0, %1" : "=v"(r) : "v"(v)); return r;
}
__device__ __forceinline__ unsigned short bf16_rne(float v) {
    unsigned u = __float_as_uint(v);
    unsigned r = u + 0x7FFFu + ((u >> 16) & 1u);
    return (unsigned short)(r >> 16);
}
__device__ __forceinline__ float bf2f(short s) {
    return __uint_as_float(((unsigned)(unsigned short)s) << 16);
}

// ---------------- kpack: W (128x128 fp32) -> bf16 hi/lo in MFMA B-fragment order
__global__ __launch_bounds__(256) void kpack(const float* __restrict__ W1,
                                             const float* __restrict__ W3,
                                             unsigned short* __restrict__ W1h,
                                             unsigned short* __restrict__ W1l,
                                             unsigned short* __restrict__ W3h,
                                             unsigned short* __restrict__ W3l) {
    const float* W = blockIdx.x ? W3 : W1;
    unsigned short* Ph = blockIdx.x ? W3h : W1h;
    unsigned short* Pl = blockIdx.x ? W3l : W1l;
    for (int i = threadIdx.x; i < 16384; i += 256) {
        int oct = i >> 10, col = (i >> 3) & 127, j = i & 7;
        float v = W[(oct * 8 + j) * 128 + col];
        unsigned short hb = bf16_rne(v);
        float hf = __uint_as_float((unsigned)hb << 16);
        Ph[i] = hb;
        Pl[i] = bf16_rne(v - hf);
    }
}

// ---------------- K0: pack mask to bits (row-major + col-major) + no-edge flags
__global__ __launch_bounds__(256) void k0_bits(const float* __restrict__ adj,
                                               unsigned* __restrict__ bits,
                                               unsigned* __restrict__ bitsT,
                                               unsigned* __restrict__ flags) {
    __shared__ unsigned lbits[64][8];
    int n  = blockIdx.x >> 3;
    int l0 = (blockIdx.x & 7) * 64;
    int lane = threadIdx.x & 63;
    int wv   = threadIdx.x >> 6;
    for (int r = wv; r < 64; r += 4) {
        int l = l0 + r;
        const float* row = adj + ((size_t)n * LL + l) * PP;
        int cnt = 0;
        for (int c = 0; c < 4; ++c) {
            float v = row[c * 64 + lane];
            unsigned long long b = __ballot(v != 0.0f);
            if (lane == 0) {
                lbits[r][c * 2]     = (unsigned)b;
                lbits[r][c * 2 + 1] = (unsigned)(b >> 32);
                cnt += __popcll(b);
            }
        }
        if (lane == 0) {
            flags[n * LL + l] = (cnt == 0) ? 1u : 0u;
            for (int w = 0; w < 8; ++w)
                bits[((size_t)n * LL + l) * 8 + w] = lbits[r][w];
        }
    }
    __syncthreads();
    int p = threadIdx.x;
    unsigned w0 = 0, w1 = 0;
    int wp = p >> 5, bp = p & 31;
    for (int j = 0; j < 32; ++j) {
        w0 |= ((lbits[j][wp] >> bp) & 1u) << j;
        w1 |= ((lbits[j + 32][wp] >> bp) & 1u) << j;
    }
    bitsT[((size_t)n * PP + p) * 16 + (l0 >> 5)]     = w0;
    bitsT[((size_t)n * PP + p) * 16 + (l0 >> 5) + 1] = w1;
}

// ---------------- gemm1c: xh = x@W1+b1; phase-split: MFMA (K-half staged) -> tbuf bf16 k-packed
// -> per-row gelu sums + in-block head softmax (sb, eu) -> xhb global. No fp32 xh artifact.
__global__ __launch_bounds__(256) void gemm1c(const float* __restrict__ A,
                                              const unsigned short* __restrict__ Bhi,
                                              const unsigned short* __restrict__ Blo,
                                              const float* __restrict__ bias,
                                              const float* __restrict__ W2,
                                              const float* __restrict__ W4,
                                              unsigned short* __restrict__ xhb,
                                              unsigned short* __restrict__ sb,
                                              float* __restrict__ eu) {
    __shared__ __align__(16) char buf[32768];   // As half (32 KB) then tbuf (32 KB)
    __shared__ float rs[128][2];
    float* As = (float*)buf;
    unsigned short* tbuf = (unsigned short*)buf;
    int tid = threadIdx.x, lane = tid & 63, w = tid >> 6;
    int b = blockIdx.x;
    size_t blockRow0 = (size_t)b * 128;
    int rl = lane & 15, g = lane >> 4;

    f32x4 acc[2][8];
    #pragma unroll
    for (int t = 0; t < 2; ++t)
        #pragma unroll
        for (int nt = 0; nt < 8; ++nt) acc[t][nt] = (f32x4){0.f, 0.f, 0.f, 0.f};

    #pragma unroll
    for (int kh = 0; kh < 2; ++kh) {
        if (kh) __syncthreads();
        {   // stage 128 rows x 64 cols fp32, coalesced, row-swizzled
            const float* Ag = A + blockRow0 * 128 + kh * 64;
            #pragma unroll
            for (int i = 0; i < 8; ++i) {
                int idx = i * 256 + tid;
                int row = idx >> 4, c4 = idx & 15;
                f32x4 v = *(const f32x4*)(Ag + (size_t)row * 128 + c4 * 4);
                *(f32x4*)((char*)As + ((row * 256 + c4 * 16) ^ ((row & 7) << 5))) = v;
            }
        }
        __syncthreads();
        #pragma unroll
        for (int kcl = 0; kcl < 2; ++kcl) {
            int kc = kh * 2 + kcl;
            short8 ah[2], al[2];
            #pragma unroll
            for (int t = 0; t < 2; ++t) {
                int arow = w * 32 + t * 16 + rl;
                int cb = (kcl * 32 + g * 8) * 4;
                int sw = (arow & 7) << 5;
                f32x4 a0 = *(const f32x4*)((char*)As + ((arow * 256 + cb) ^ sw));
                f32x4 a1 = *(const f32x4*)((char*)As + ((arow * 256 + cb + 16) ^ sw));
                float av[8] = {a0.x, a0.y, a0.z, a0.w, a1.x, a1.y, a1.z, a1.w};
                #pragma unroll
                for (int j = 0; j < 8; ++j) {
                    unsigned short hb = bf16_rne(av[j]);
                    float hf = __uint_as_float((unsigned)hb << 16);
                    ah[t][j] = (short)hb;
                    al[t][j] = (short)bf16_rne(av[j] - hf);
                }
            }
            #pragma unroll
            for (int nt = 0; nt < 8; ++nt) {
                int oct = kc * 4 + g, col = nt * 16 + rl;
                short8 bh = *(const short8*)(Bhi + ((size_t)(oct * 128 + col)) * 8);
                short8 bl = *(const short8*)(Blo + ((size_t)(oct * 128 + col)) * 8);
                #pragma unroll
                for (int t = 0; t < 2; ++t) {
                    acc[t][nt] = __builtin_amdgcn_mfma_f32_16x16x32_bf16(ah[t], bh, acc[t][nt], 0, 0, 0);
                    acc[t][nt] = __builtin_amdgcn_mfma_f32_16x16x32_bf16(ah[t], bl, acc[t][nt], 0, 0, 0);
                    acc[t][nt] = __builtin_amdgcn_mfma_f32_16x16x32_bf16(al[t], bh, acc[t][nt], 0, 0, 0);
                }
            }
        }
    }
    __syncthreads();   // As dead; buf becomes tbuf

    // Phase B: acc -> tbuf[h][kg][e][lpos] bf16 (acc dies here; no extra accumulators)
    #pragma unroll
    for (int nt = 0; nt < 8; ++nt) {
        int col = nt * 16 + rl;
        float bv = bias[col];
        #pragma unroll
        for (int t = 0; t < 2; ++t) {
            int l_loc = w * 4 + t * 2 + (g >> 1);
            int kg = l_loc >> 3, lpos = l_loc & 7;
            #pragma unroll
            for (int r = 0; r < 4; ++r) {
                int h = (g * 4 + r) & 7;
                tbuf[(((h * 2 + kg) * 128 + col) << 3) + lpos] = bf16_rne(acc[t][nt][r] + bv);
            }
        }
    }
    __syncthreads();

    // Phase C: per-row gelu sums (fresh registers) + in-block head softmax
    {
        int row_loc = tid >> 1, half = tid & 1;
        int h = row_loc & 7, l_loc = row_loc >> 3;
        int kg = l_loc >> 3, lpos = l_loc & 7;
        const unsigned short* tb = tbuf + (((h * 2 + kg) * 128) << 3) + lpos;
        float xv = 0.f, an = 0.f;
        #pragma unroll 8
        for (int e = half * 64; e < half * 64 + 64; ++e) {
            float gv = gelu_f(bf2f((short)tb[e << 3]));
            xv += gv * W2[e];
            an += gv * W4[128 + e];
        }
        xv += __shfl_xor(xv, 1);
        an += __shfl_xor(an, 1);
        if (half == 0) { rs[row_loc][0] = xv; rs[row_loc][1] = an; }
    }
    __syncthreads();
    int n = b >> 5;
    if (tid < 16) {
        int l = (b & 31) * 16 + tid;
        float xv[8], an[8];
        #pragma unroll
        for (int h = 0; h < 8; ++h) { xv[h] = rs[tid * 8 + h][0]; an[h] = rs[tid * 8 + h][1]; }
        float mx = xv[0];
        #pragma unroll
        for (int h = 1; h < 8; ++h) mx = fmaxf(mx, xv[h]);
        float ex[8], ssum = 0.f;
        #pragma unroll
        for (int h = 0; h < 8; ++h) { ex[h] = expf(xv[h] - mx); ssum += ex[h]; }
        float inv = 1.0f / ssum;
        #pragma unroll
        for (int h = 0; h < 8; ++h)
            sb[((size_t)(n * 8 + h)) * 512 + l] = bf16_rne(ex[h] * inv);
        float mxa = an[0];
        #pragma unroll
        for (int h = 1; h < 8; ++h) mxa = fmaxf(mxa, an[h]);
        f32x4 e0, e1;
        #pragma unroll
        for (int h = 0; h < 4; ++h) e0[h] = expf(an[h] - mxa);
        #pragma unroll
        for (int h = 0; h < 4; ++h) e1[h] = expf(an[4 + h] - mxa);
        float* ep = eu + ((size_t)(n * 512 + l)) * 8;
        *(f32x4*)ep = e0;
        *(f32x4*)(ep + 4) = e1;
    }

    // Phase D: tbuf -> xhb (vector short8, coalesced)
    int kg0 = (b & 31) * 2;
    #pragma unroll
    for (int rep = 0; rep < 8; ++rep) {
        int id = rep * 256 + tid;
        int h = id >> 8, kg = (id >> 7) & 1, e = id & 127;
        short8 v = *(const short8*)&tbuf[(((h * 2 + kg) * 128 + e) << 3)];
        *(short8*)(xhb + ((size_t)(n * 8 + h)) * 65536 + (size_t)((kg0 + kg) * 128 + e) * 8) = v;
    }
}

// ---------------- k2_mfma: heg = gelu(A' @ xh); xhb bf16 k-packed input; 1024 threads
__global__ __launch_bounds__(1024) void k2_mfma(const unsigned short* __restrict__ xhb,
                                                const unsigned short* __restrict__ s_in,
                                                const unsigned* __restrict__ bitsT,
                                                float* __restrict__ heg) {
    __shared__ __align__(16) unsigned short kpk[65536];    // 128 KB
    __shared__ unsigned bT_s[16 * 256];                    // [kt][p], 16 KB
    __shared__ __align__(16) unsigned short smb_s[512];    // bf16(s), 1 KB
    int bh = blockIdx.x;
    int n = bh >> 3;
    int tid = threadIdx.x, lane = tid & 63, w = tid >> 6;

    {
        int p = tid >> 2, q = tid & 3;
        uint4 wds = *(const uint4*)(bitsT + ((size_t)(n * 256 + p)) * 16 + q * 4);
        bT_s[(q * 4 + 0) * 256 + p] = wds.x;
        bT_s[(q * 4 + 1) * 256 + p] = wds.y;
        bT_s[(q * 4 + 2) * 256 + p] = wds.z;
        bT_s[(q * 4 + 3) * 256 + p] = wds.w;
    }
    if (tid < 512) smb_s[tid] = s_in[(size_t)bh * 512 + tid];
    {
        const unsigned short* xb = xhb + (size_t)bh * 65536;
        #pragma unroll
        for (int rep = 0; rep < 8; ++rep) {
            int idx = rep * 1024 + tid;
            *(short8*)&kpk[idx * 8] = *(const short8*)(xb + (size_t)idx * 8);
        }
    }
    __syncthreads();

    int rl = lane & 15, g = lane >> 4;
    int wm = w & 7, wn = w >> 3;
    f32x4 acc[2][4];
    #pragma unroll
    for (int i = 0; i < 2; ++i)
        #pragma unroll
        for (int nt = 0; nt < 4; ++nt) acc[i][nt] = (f32x4){0.f, 0.f, 0.f, 0.f};

    for (int kt = 0; kt < 16; ++kt) {
        short8 sv = *(const short8*)&smb_s[kt * 32 + g * 8];
        short8 bfr[4];
        #pragma unroll
        for (int nt = 0; nt < 4; ++nt)
            bfr[nt] = *(const short8*)&kpk[(((kt * 4 + g) << 7) + wn * 64 + nt * 16 + rl) * 8];
        #pragma unroll
        for (int i = 0; i < 2; ++i) {
            unsigned word = bT_s[kt * 256 + (wm * 2 + i) * 16 + rl];
            unsigned byte = (word >> (g * 8)) & 255u;
            short8 af;
            #pragma unroll
            for (int j = 0; j < 8; ++j)
                af[j] = ((byte >> j) & 1u) ? sv[j] : (short)0x3E00;
            #pragma unroll
            for (int nt = 0; nt < 4; ++nt)
                acc[i][nt] = __builtin_amdgcn_mfma_f32_16x16x32_bf16(af, bfr[nt], acc[i][nt], 0, 0, 0);
        }
    }

    float* ob = heg + (size_t)bh * (PP * EE);
    #pragma unroll
    for (int i = 0; i < 2; ++i)
        #pragma unroll
        for (int nt = 0; nt < 4; ++nt) {
            int e = wn * 64 + nt * 16 + rl;
            #pragma unroll
            for (int r = 0; r < 4; ++r) {
                int p = (wm * 2 + i) * 16 + g * 4 + r;
                ob[(size_t)p * 128 + e] = gelu_f(acc[i][nt][r]);
            }
        }
}

// ---------------- gemm3: he = heg@W3+b3 in-register (K-half staged); fused ev + heT bf16 transpose
__global__ __launch_bounds__(256) void gemm3(const float* __restrict__ A,
                                             const unsigned short* __restrict__ Bhi,
                                             const unsigned short* __restrict__ Blo,
                                             const float* __restrict__ bias,
                                             const float* __restrict__ W4,
                                             unsigned short* __restrict__ heT,
                                             float* __restrict__ ev) {
    __shared__ __align__(16) char buf[32768];   // As half (32 KB) then tbuf (32 KB)
    __shared__ float rs_ae[128];
    float* As = (float*)buf;
    unsigned short* tbuf = (unsigned short*)buf;
    int tid = threadIdx.x, lane = tid & 63, w = tid >> 6;
    size_t blockRow0 = (size_t)blockIdx.x * 128;
    int rl = lane & 15, g = lane >> 4;

    f32x4 acc[2][8];
    #pragma unroll
    for (int t = 0; t < 2; ++t)
        #pragma unroll
        for (int nt = 0; nt < 8; ++nt) acc[t][nt] = (f32x4){0.f, 0.f, 0.f, 0.f};

    #pragma unroll
    for (int kh = 0; kh < 2; ++kh) {
        if (kh) __syncthreads();
        {
            const float* Ag = A + blockRow0 * 128 + kh * 64;
            #pragma unroll
            for (int i = 0; i < 8; ++i) {
                int idx = i * 256 + tid;
                int row = idx >> 4, c4 = idx & 15;
                f32x4 v = *(const f32x4*)(Ag + (size_t)row * 128 + c4 * 4);
                *(f32x4*)((char*)As + ((row * 256 + c4 * 16) ^ ((row & 7) << 5))) = v;
            }
        }
        __syncthreads();
        #pragma unroll
        for (int kcl = 0; kcl < 2; ++kcl) {
            int kc = kh * 2 + kcl;
            short8 ah[2], al[2];
            #pragma unroll
            for (int t = 0; t < 2; ++t) {
                int arow = w * 32 + t * 16 + rl;
                int cb = (kcl * 32 + g * 8) * 4;
                int sw = (arow & 7) << 5;
                f32x4 a0 = *(const f32x4*)((char*)As + ((arow * 256 + cb) ^ sw));
                f32x4 a1 = *(const f32x4*)((char*)As + ((arow * 256 + cb + 16) ^ sw));
                float av[8] = {a0.x, a0.y, a0.z, a0.w, a1.x, a1.y, a1.z, a1.w};
                #pragma unroll
                for (int j = 0; j < 8; ++j) {
                    unsigned short hb = bf16_rne(av[j]);
                    float hf = __uint_as_float((unsigned)hb << 16);
                    ah[t][j] = (short)hb;
                    al[t][j] = (short)bf16_rne(av[j] - hf);
                }
            }
            #pragma unroll
            for (int nt = 0; nt < 8; ++nt) {
                int oct = kc * 4 + g, col = nt * 16 + rl;
                short8 bh = *(const short8*)(Bhi + ((size_t)(oct * 128 + col)) * 8);
                short8 bl = *(const short8*)(Blo + ((size_t)(oct * 128 + col)) * 8);
                #pragma unroll
                for (int t = 0; t < 2; ++t) {
                    acc[t][nt] = __builtin_amdgcn_mfma_f32_16x16x32_bf16(ah[t], bh, acc[t][nt], 0, 0, 0);
                    acc[t][nt] = __builtin_amdgcn_mfma_f32_16x16x32_bf16(ah[t], bl, acc[t][nt], 0, 0, 0);
                    acc[t][nt] = __builtin_amdgcn_mfma_f32_16x16x32_bf16(al[t], bh, acc[t][nt], 0, 0, 0);
                }
            }
        }
    }
    __syncthreads();   // As dead; buf becomes tbuf

    float ae_p[2][4] = {{0.f,0.f,0.f,0.f},{0.f,0.f,0.f,0.f}};
    #pragma unroll
    for (int nt = 0; nt < 8; ++nt) {
        int col = nt * 16 + rl;
        float bv = bias[col], w4v = W4[col];
        #pragma unroll
        for (int t = 0; t < 2; ++t) {
            float v0 = acc[t][nt][0] + bv;
            float v1 = acc[t][nt][1] + bv;
            float v2 = acc[t][nt][2] + bv;
            float v3 = acc[t][nt][3] + bv;
            ae_p[t][0] += gelu_f(v0) * w4v;
            ae_p[t][1] += gelu_f(v1) * w4v;
            ae_p[t][2] += gelu_f(v2) * w4v;
            ae_p[t][3] += gelu_f(v3) * w4v;
            int row_loc = w * 32 + t * 16 + g * 4;
            int byte = (col * 256 + row_loc * 2) ^ ((col & 7) << 4);
            *(ushort4*)((char*)tbuf + byte) =
                make_ushort4(bf16_rne(v0), bf16_rne(v1), bf16_rne(v2), bf16_rne(v3));
        }
    }
    #pragma unroll
    for (int t = 0; t < 2; ++t)
        #pragma unroll
        for (int r = 0; r < 4; ++r) {
            float a = ae_p[t][r];
            a += __shfl_xor(a, 1); a += __shfl_xor(a, 2); a += __shfl_xor(a, 4); a += __shfl_xor(a, 8);
            if (rl == 0) rs_ae[w * 32 + t * 16 + g * 4 + r] = a;
        }
    __syncthreads();
    int bh2 = blockIdx.x >> 1, p0 = (blockIdx.x & 1) * 128;
    #pragma unroll
    for (int rep = 0; rep < 8; ++rep) {
        int id = rep * 256 + tid;
        int e = id >> 4, j = id & 15;
        int byte = (e * 256 + j * 16) ^ ((e & 7) << 4);
        short8 v = *(const short8*)((char*)tbuf + byte);
        *(short8*)(heT + (size_t)bh2 * 32768 + (size_t)e * 256 + p0 + j * 8) = v;
    }
    if (tid < 128) {
        int row = blockIdx.x * 128 + tid;
        int n = row >> 11, h = (row >> 8) & 7, p = row & 255;
        ev[((size_t)(n * 256 + p)) * 8 + h] = expf(rs_ae[tid]);
    }
}

// ---------------- k4_dense: rdm[n][l][p] = bit ? 1/den : 0  (bf16, h-shared)
__global__ __launch_bounds__(256) void k4_dense(const float* __restrict__ eu,
                                                const float* __restrict__ ev,
                                                const unsigned* __restrict__ bits,
                                                unsigned short* __restrict__ rdm) {
    __shared__ float ev_t[256][8];
    int b = blockIdx.x;
    int n = b >> 3, l0 = (b & 7) * 64;
    int tid = threadIdx.x;
    {
        const f32x4* src = (const f32x4*)(ev + (size_t)n * 2048);
        f32x4* dst = (f32x4*)&ev_t[0][0];
        dst[tid] = src[tid];
        dst[tid + 256] = src[tid + 256];
    }
    __syncthreads();
    int l = l0 + (tid >> 2), pq = tid & 3;
    size_t rowg = (size_t)n * 512 + l;
    f32x4 ea = *(const f32x4*)(eu + rowg * 8);
    f32x4 eb = *(const f32x4*)(eu + rowg * 8 + 4);
    unsigned w0 = bits[rowg * 8 + pq * 2], w1 = bits[rowg * 8 + pq * 2 + 1];
    for (int c = 0; c < 8; ++c) {
        short8 o8;
        #pragma unroll
        for (int k = 0; k < 8; ++k) {
            int pl = c * 8 + k;
            int p = pq * 64 + pl;
            f32x4 va = *(const f32x4*)&ev_t[p][0];
            f32x4 vb = *(const f32x4*)&ev_t[p][4];
            float den = ea.x * va.x + ea.y * va.y + ea.z * va.z + ea.w * va.w
                      + eb.x * vb.x + eb.y * vb.y + eb.z * vb.z + eb.w * vb.w;
            unsigned bit = (pl < 32) ? ((w0 >> pl) & 1u) : ((w1 >> (pl - 32)) & 1u);
            float r = bit ? rcp_f(den) : 0.0f;
            o8[k] = (short)bf16_rne(r);
        }
        *(short8*)(rdm + rowg * 256 + pq * 64 + c * 8) = o8;
    }
}

// ---------------- k5_mfma: x_nodes = 0.125*colsum(he) + A @ he; 1024 threads (16 waves)
__global__ __launch_bounds__(1024) void k5_mfma(const unsigned short* __restrict__ heT,
                                                const unsigned short* __restrict__ rdm,
                                                const float* __restrict__ eu,
                                                const float* __restrict__ ev,
                                                const unsigned* __restrict__ flags,
                                                const float* __restrict__ x,
                                                float* __restrict__ out) {
    __shared__ __align__(16) unsigned short heT_s[128 * 256];  // swizzled [e][p], 64 KB
    __shared__ __align__(16) unsigned short A_s[64 * 256];     // swizzled [l_loc][p], 32 KB
    __shared__ float evh_s[256];
    __shared__ float euh_s[64];
    __shared__ float cs_s[128];
    __shared__ float csr_s[4][128];
    __shared__ unsigned flg_s[64];

    int bid = blockIdx.x;
    int xcd = bid & 7, slot = bid >> 3;          // group 8 heads of same n per XCD (rdm L2 reuse)
    int n = xcd * 4 + (slot & 3), h = slot >> 2;
    int bh = n * 8 + h;
    int tid = threadIdx.x, lane = tid & 63, w = tid >> 6;

    const unsigned short* hb = heT + (size_t)bh * 32768;
    #pragma unroll
    for (int i = 0; i < 4; ++i) {
        int id = tid + i * 1024;
        int e = id >> 5, jj = id & 31;
        short8 v = *(const short8*)(hb + e * 256 + jj * 8);
        *(short8*)((char*)heT_s + ((e * 512 + jj * 16) ^ ((e & 7) << 4))) = v;
    }
    if (tid < 256) evh_s[tid] = ev[((size_t)(n * 256 + tid)) * 8 + h];
    __syncthreads();
    if (tid < 512) {
        int e = tid & 127, q = tid >> 7;
        float a = 0.f;
        #pragma unroll
        for (int j = 0; j < 8; ++j) {
            int byte = (e * 512 + (q * 64 + j * 8) * 2) ^ ((e & 7) << 4);
            short8 v = *(const short8*)((char*)heT_s + byte);
            #pragma unroll
            for (int k = 0; k < 8; ++k) a += bf2f(v[k]);
        }
        csr_s[q][e] = a;
    }
    __syncthreads();
    if (tid < 128) cs_s[tid] = 0.125f * (csr_s[0][tid] + csr_s[1][tid] + csr_s[2][tid] + csr_s[3][tid]);

    int rl = lane & 15, g = lane >> 4;
    int wm = w & 3, wn = w >> 2;       // 4 mt x 4 e-groups (2 nt each)
    int swz = (rl & 7) << 4;

    for (int lt = 0; lt < 8; ++lt) {
        int l0 = lt * 64;
        if (tid < 64) {
            euh_s[tid] = eu[((size_t)(n * 512 + l0 + tid)) * 8 + h];
            flg_s[tid] = flags[n * 512 + l0 + tid];
        }
        __syncthreads();
        {
            int l_loc = tid >> 4, p8 = (tid & 15) * 16;
            float euh = euh_s[l_loc];
            const unsigned short* rp = rdm + ((size_t)(n * 512 + l0 + l_loc)) * 256 + p8;
            #pragma unroll
            for (int c = 0; c < 2; ++c) {
                short8 rv = *(const short8*)(rp + c * 8);
                short8 o8;
                #pragma unroll
                for (int k = 0; k < 8; ++k) {
                    unsigned u = (unsigned)(unsigned short)rv[k];
                    float rf = __uint_as_float(u << 16);
                    float m125 = (u != 0u) ? -0.125f : 0.0f;
                    float a = fmaf(euh * evh_s[p8 + c * 8 + k], rf, m125);
                    o8[k] = (short)bf16_rne(a);
                }
                *(short8*)((char*)A_s + ((l_loc * 512 + (p8 + c * 8) * 2) ^ ((l_loc & 7) << 4))) = o8;
            }
        }
        __syncthreads();
        f32x4 acc[2];
        acc[0] = (f32x4){0.f, 0.f, 0.f, 0.f};
        acc[1] = (f32x4){0.f, 0.f, 0.f, 0.f};
        #pragma unroll
        for (int kt = 0; kt < 8; ++kt) {
            int arow = wm * 16 + rl;
            short8 af = *(const short8*)((char*)A_s + ((arow * 512 + kt * 64 + g * 16) ^ swz));
            short8 b0, b1;
            {
                int e0 = wn * 32 + rl;
                int e1 = wn * 32 + 16 + rl;
                b0 = *(const short8*)((char*)heT_s + ((e0 * 512 + kt * 64 + g * 16) ^ swz));
                b1 = *(const short8*)((char*)heT_s + ((e1 * 512 + kt * 64 + g * 16) ^ swz));
            }
            acc[0] = __builtin_amdgcn_mfma_f32_16x16x32_bf16(af, b0, acc[0], 0, 0, 0);
            acc[1] = __builtin_amdgcn_mfma_f32_16x16x32_bf16(af, b1, acc[1], 0, 0, 0);
        }
        #pragma unroll
        for (int j = 0; j < 2; ++j) {
            int e = wn * 32 + j * 16 + rl;
            float csv = cs_s[e];
            #pragma unroll
            for (int r = 0; r < 4; ++r) {
                int row = wm * 16 + g * 4 + r;
                int l = l0 + row;
                size_t addr = ((size_t)(n * 512 + l)) * 1024 + h * 128 + e;
                if (flg_s[row]) {
                    out[addr] = x[addr];
                } else {
                    out[addr] = gelu_f(acc[j][r] + csv);
                }
            }
        }
        __syncthreads();
    }
}

extern "C" void kernel_launch(void* const* d_in, const int* in_sizes, int n_in,
                              void* d_out, int out_size, void* d_ws, size_t ws_size,
                              hipStream_t stream) {
    (void)in_sizes; (void)n_in; (void)out_size; (void)ws_size;
    const float* x   = (const float*)d_in[0];
    const float* adj = (const float*)d_in[1];
    const float* W1  = (const float*)d_in[2];
    const float* b1  = (const float*)d_in[3];
    const float* W2  = (const float*)d_in[4];
    const float* W3  = (const float*)d_in[6];
    const float* b3  = (const float*)d_in[7];
    const float* W4  = (const float*)d_in[8];
    float* out = (float*)d_out;

    char* ws = (char*)d_ws;
    size_t off = 0;
    auto alloc = [&](size_t bytes) -> void* {
        void* p = ws + off;
        off += (bytes + 255) & ~(size_t)255;
        return p;
    };
    unsigned short* xhb = (unsigned short*)alloc((size_t)NB * HH * 65536 * 2);   // 33.5 MB bf16 k-packed
    unsigned short* sb  = (unsigned short*)alloc((size_t)NB * HH * LL * 2);      // bf16 s
    float* eu   = (float*)alloc((size_t)NB * LL * HH * 4);
    float* ev   = (float*)alloc((size_t)NB * PP * HH * 4);
    float* heg  = (float*)alloc((size_t)NB * HH * PP * EE * 4);                  // 33.5 MB
    unsigned short* heT = (unsigned short*)alloc((size_t)NB * HH * EE * PP * 2); // 16.8 MB [(n,h)][e][p]
    unsigned short* rdm = (unsigned short*)alloc((size_t)NB * LL * PP * 2);      // 8.4 MB [n][l][p]
    unsigned* bits  = (unsigned*)alloc((size_t)NB * LL * 8 * 4);
    unsigned* bitsT = (unsigned*)alloc((size_t)NB * PP * 16 * 4);
    unsigned* flags = (unsigned*)alloc((size_t)NB * LL * 4);
    unsigned short* W1h = (unsigned short*)alloc(16384 * 2);
    unsigned short* W1l = (unsigned short*)alloc(16384 * 2);
    unsigned short* W3h = (unsigned short*)alloc(16384 * 2);
    unsigned short* W3l = (unsigned short*)alloc(16384 * 2);

    hipLaunchKernelGGL(kpack, dim3(2), dim3(256), 0, stream, W1, W3, W1h, W1l, W3h, W3l);
    hipLaunchKernelGGL(k0_bits, dim3(NB * 8), dim3(256), 0, stream, adj, bits, bitsT, flags);
    hipLaunchKernelGGL(gemm1c, dim3(1024), dim3(256), 0, stream, x, W1h, W1l, b1, W2, W4, xhb, sb, eu);
    hipLaunchKernelGGL(k2_mfma, dim3(NB * HH), dim3(1024), 0, stream, xhb, sb, bitsT, heg);
    hipLaunchKernelGGL(gemm3, dim3(512), dim3(256), 0, stream, heg, W3h, W3l, b3, W4, heT, ev);
    hipLaunchKernelGGL(k4_dense, dim3(NB * 8), dim3(256), 0, stream, eu, ev, bits, rdm);
    hipLaunchKernelGGL(k5_mfma, dim3(NB * HH), dim3(1024), 0, stream, heT, rdm, eu, ev, flags, x, out);
}

// Round 13
// 208.422 us; speedup vs baseline: 1.3095x; 1.0382x over previous
//
#include <hip/hip_runtime.h>
#include <math.h>

#define NB 32
#define LL 512
#define PP 256
#define HH 8
#define EE 128
#define DD 1024

typedef __attribute__((ext_vector_type(4))) float f32x4;
typedef __attribute__((ext_vector_type(8))) short short8;

__device__ __forceinline__ float gelu_f(float v) {
    return 0.5f * v * (1.0f + erff(v * 0.70710678118654752f));
}
__device__ __forceinline__ float rcp_f(float v) {
    float r; asm("v_rcp_f32 %0, %1" : "=v"(r) : "v"(v)); return r;
}
__device__ __forceinline__ unsigned short bf16_rne(float v) {
    unsigned u = __float_as_uint(v);
    unsigned r = u + 0x7FFFu + ((u >> 16) & 1u);
    return (unsigned short)(r >> 16);
}
__device__ __forceinline__ float bf2f(short s) {
    return __uint_as_float(((unsigned)(unsigned short)s) << 16);
}

// ---------------- kpack: W (128x128 fp32) -> bf16 hi/lo in MFMA B-fragment order
__global__ __launch_bounds__(256) void kpack(const float* __restrict__ W1,
                                             const float* __restrict__ W3,
                                             unsigned short* __restrict__ W1h,
                                             unsigned short* __restrict__ W1l,
                                             unsigned short* __restrict__ W3h,
                                             unsigned short* __restrict__ W3l) {
    const float* W = blockIdx.x ? W3 : W1;
    unsigned short* Ph = blockIdx.x ? W3h : W1h;
    unsigned short* Pl = blockIdx.x ? W3l : W1l;
    for (int i = threadIdx.x; i < 16384; i += 256) {
        int oct = i >> 10, col = (i >> 3) & 127, j = i & 7;
        float v = W[(oct * 8 + j) * 128 + col];
        unsigned short hb = bf16_rne(v);
        float hf = __uint_as_float((unsigned)hb << 16);
        Ph[i] = hb;
        Pl[i] = bf16_rne(v - hf);
    }
}

// ---------------- K0: pack mask to bits (row-major + col-major) + no-edge flags
__global__ __launch_bounds__(256) void k0_bits(const float* __restrict__ adj,
                                               unsigned* __restrict__ bits,
                                               unsigned* __restrict__ bitsT,
                                               unsigned* __restrict__ flags) {
    __shared__ unsigned lbits[64][8];
    int n  = blockIdx.x >> 3;
    int l0 = (blockIdx.x & 7) * 64;
    int lane = threadIdx.x & 63;
    int wv   = threadIdx.x >> 6;
    for (int r = wv; r < 64; r += 4) {
        int l = l0 + r;
        const float* row = adj + ((size_t)n * LL + l) * PP;
        int cnt = 0;
        for (int c = 0; c < 4; ++c) {
            float v = row[c * 64 + lane];
            unsigned long long b = __ballot(v != 0.0f);
            if (lane == 0) {
                lbits[r][c * 2]     = (unsigned)b;
                lbits[r][c * 2 + 1] = (unsigned)(b >> 32);
                cnt += __popcll(b);
            }
        }
        if (lane == 0) {
            flags[n * LL + l] = (cnt == 0) ? 1u : 0u;
            for (int w = 0; w < 8; ++w)
                bits[((size_t)n * LL + l) * 8 + w] = lbits[r][w];
        }
    }
    __syncthreads();
    int p = threadIdx.x;
    unsigned w0 = 0, w1 = 0;
    int wp = p >> 5, bp = p & 31;
    for (int j = 0; j < 32; ++j) {
        w0 |= ((lbits[j][wp] >> bp) & 1u) << j;
        w1 |= ((lbits[j + 32][wp] >> bp) & 1u) << j;
    }
    bitsT[((size_t)n * PP + p) * 16 + (l0 >> 5)]     = w0;
    bitsT[((size_t)n * PP + p) * 16 + (l0 >> 5) + 1] = w1;
}

// ---------------- gemm1c: xh = x@W1+b1; 1024 thr / 16 waves; tbuf [l_loc][e][h] bf16
// Phase A: MFMA (K-half staged As). Phase B: acc->tbuf (ushort4, conflict-free).
// Phase C: per-row gelu sums via b128 reads (quarter-aligned). Softmax in-block. Phase D: k-pack to xhb.
__global__ __launch_bounds__(1024) void gemm1c(const float* __restrict__ A,
                                               const unsigned short* __restrict__ Bhi,
                                               const unsigned short* __restrict__ Blo,
                                               const float* __restrict__ bias,
                                               const float* __restrict__ W2,
                                               const float* __restrict__ W4,
                                               unsigned short* __restrict__ xhb,
                                               unsigned short* __restrict__ sb,
                                               float* __restrict__ eu) {
    __shared__ __align__(16) char buf[32768];   // As half (32 KB) then tbuf (32 KB)
    __shared__ float rs4[4][128][2];
    __shared__ float rs[128][2];
    float* As = (float*)buf;
    unsigned short* tbuf = (unsigned short*)buf;
    int tid = threadIdx.x, lane = tid & 63, w = tid >> 6;
    int b = blockIdx.x;
    size_t blockRow0 = (size_t)b * 128;
    int rl = lane & 15, g = lane >> 4;
    int mt = w & 7, eh = w >> 3;

    f32x4 acc[4];
    #pragma unroll
    for (int nt = 0; nt < 4; ++nt) acc[nt] = (f32x4){0.f, 0.f, 0.f, 0.f};

    #pragma unroll
    for (int kh = 0; kh < 2; ++kh) {
        if (kh) __syncthreads();
        {   // stage 128 rows x 64 cols fp32, coalesced, row-swizzled
            const float* Ag = A + blockRow0 * 128 + kh * 64;
            #pragma unroll
            for (int i = 0; i < 2; ++i) {
                int idx = i * 1024 + tid;
                int row = idx >> 4, c4 = idx & 15;
                f32x4 v = *(const f32x4*)(Ag + (size_t)row * 128 + c4 * 4);
                *(f32x4*)((char*)As + ((row * 256 + c4 * 16) ^ ((row & 7) << 5))) = v;
            }
        }
        __syncthreads();
        #pragma unroll
        for (int kcl = 0; kcl < 2; ++kcl) {
            int kc = kh * 2 + kcl;
            short8 ah, al;
            {
                int arow = mt * 16 + rl;
                int cb = (kcl * 32 + g * 8) * 4;
                int sw = (arow & 7) << 5;
                f32x4 a0 = *(const f32x4*)((char*)As + ((arow * 256 + cb) ^ sw));
                f32x4 a1 = *(const f32x4*)((char*)As + ((arow * 256 + cb + 16) ^ sw));
                float av[8] = {a0.x, a0.y, a0.z, a0.w, a1.x, a1.y, a1.z, a1.w};
                #pragma unroll
                for (int j = 0; j < 8; ++j) {
                    unsigned short hb = bf16_rne(av[j]);
                    float hf = __uint_as_float((unsigned)hb << 16);
                    ah[j] = (short)hb;
                    al[j] = (short)bf16_rne(av[j] - hf);
                }
            }
            #pragma unroll
            for (int ntl = 0; ntl < 4; ++ntl) {
                int oct = kc * 4 + g, col = eh * 64 + ntl * 16 + rl;
                short8 bh = *(const short8*)(Bhi + ((size_t)(oct * 128 + col)) * 8);
                short8 bl = *(const short8*)(Blo + ((size_t)(oct * 128 + col)) * 8);
                acc[ntl] = __builtin_amdgcn_mfma_f32_16x16x32_bf16(ah, bh, acc[ntl], 0, 0, 0);
                acc[ntl] = __builtin_amdgcn_mfma_f32_16x16x32_bf16(ah, bl, acc[ntl], 0, 0, 0);
                acc[ntl] = __builtin_amdgcn_mfma_f32_16x16x32_bf16(al, bh, acc[ntl], 0, 0, 0);
            }
        }
    }
    __syncthreads();   // As dead; buf becomes tbuf

    // Phase B: acc -> tbuf[l_loc][e][h], ushort4 (4 consecutive h), conflict-free
    {
        int l_loc = mt * 2 + (g >> 1);
        int hbase2 = (g & 1) * 8;     // byte offset of the 4-h group
        #pragma unroll
        for (int ntl = 0; ntl < 4; ++ntl) {
            int col = eh * 64 + ntl * 16 + rl;
            float bv = bias[col];
            ushort4 o;
            o.x = bf16_rne(acc[ntl][0] + bv);
            o.y = bf16_rne(acc[ntl][1] + bv);
            o.z = bf16_rne(acc[ntl][2] + bv);
            o.w = bf16_rne(acc[ntl][3] + bv);
            *(ushort4*)((char*)tbuf + (l_loc * 2048 + col * 16 + hbase2)) = o;
        }
    }
    __syncthreads();

    // Phase C: per-row gelu sums; thread = (eq, l_loc, ec); 2x b128 reads, quarter-aligned
    {
        int ec = tid & 15, l_loc = (tid >> 4) & 15, eq = tid >> 8;   // eq 0..3
        float xv_p[8] = {0,0,0,0,0,0,0,0};
        float an_p[8] = {0,0,0,0,0,0,0,0};
        #pragma unroll
        for (int i = 0; i < 2; ++i) {
            int e = (eq * 2 + i) * 16 + ec;
            short8 v = *(const short8*)((char*)tbuf + (l_loc * 2048 + e * 16));
            float w2 = W2[e], w4 = W4[128 + e];
            #pragma unroll
            for (int h = 0; h < 8; ++h) {
                float gv = gelu_f(bf2f(v[h]));
                xv_p[h] += gv * w2;
                an_p[h] += gv * w4;
            }
        }
        #pragma unroll
        for (int h = 0; h < 8; ++h) {
            #pragma unroll
            for (int m = 1; m < 16; m <<= 1) {
                xv_p[h] += __shfl_xor(xv_p[h], m);
                an_p[h] += __shfl_xor(an_p[h], m);
            }
        }
        if (ec == 0) {
            #pragma unroll
            for (int h = 0; h < 8; ++h) {
                rs4[eq][l_loc * 8 + h][0] = xv_p[h];
                rs4[eq][l_loc * 8 + h][1] = an_p[h];
            }
        }
    }

    // Phase D: tbuf -> xhb k-packed [(n,h)][kg][e][lpos]; gather over l_loc
    int n = b >> 5, kg0 = (b & 31) * 2;
    #pragma unroll
    for (int rep = 0; rep < 2; ++rep) {
        int id = rep * 1024 + tid;
        int h = (id >> 8) & 7, kg = (id >> 7) & 1, e = id & 127;
        short8 v;
        #pragma unroll
        for (int j = 0; j < 8; ++j)
            v[j] = (short)*(const unsigned short*)((char*)tbuf + ((kg * 8 + j) * 2048 + e * 16 + h * 2));
        *(short8*)(xhb + ((size_t)(n * 8 + h)) * 65536 + (size_t)((kg0 + kg) * 128 + e) * 8) = v;
    }
    __syncthreads();

    if (tid < 128) {
        rs[tid][0] = rs4[0][tid][0] + rs4[1][tid][0] + rs4[2][tid][0] + rs4[3][tid][0];
        rs[tid][1] = rs4[0][tid][1] + rs4[1][tid][1] + rs4[2][tid][1] + rs4[3][tid][1];
    }
    __syncthreads();
    if (tid < 16) {
        int l = (b & 31) * 16 + tid;
        float xv[8], an[8];
        #pragma unroll
        for (int h = 0; h < 8; ++h) { xv[h] = rs[tid * 8 + h][0]; an[h] = rs[tid * 8 + h][1]; }
        float mx = xv[0];
        #pragma unroll
        for (int h = 1; h < 8; ++h) mx = fmaxf(mx, xv[h]);
        float ex[8], ssum = 0.f;
        #pragma unroll
        for (int h = 0; h < 8; ++h) { ex[h] = expf(xv[h] - mx); ssum += ex[h]; }
        float inv = 1.0f / ssum;
        #pragma unroll
        for (int h = 0; h < 8; ++h)
            sb[((size_t)(n * 8 + h)) * 512 + l] = bf16_rne(ex[h] * inv);
        float mxa = an[0];
        #pragma unroll
        for (int h = 1; h < 8; ++h) mxa = fmaxf(mxa, an[h]);
        f32x4 e0, e1;
        #pragma unroll
        for (int h = 0; h < 4; ++h) e0[h] = expf(an[h] - mxa);
        #pragma unroll
        for (int h = 0; h < 4; ++h) e1[h] = expf(an[4 + h] - mxa);
        float* ep = eu + ((size_t)(n * 512 + l)) * 8;
        *(f32x4*)ep = e0;
        *(f32x4*)(ep + 4) = e1;
    }
}

// ---------------- k2_mfma: heg = gelu(A' @ xh); xhb bf16 k-packed input; 1024 threads
__global__ __launch_bounds__(1024) void k2_mfma(const unsigned short* __restrict__ xhb,
                                                const unsigned short* __restrict__ s_in,
                                                const unsigned* __restrict__ bitsT,
                                                float* __restrict__ heg) {
    __shared__ __align__(16) unsigned short kpk[65536];    // 128 KB
    __shared__ unsigned bT_s[16 * 256];                    // [kt][p], 16 KB
    __shared__ __align__(16) unsigned short smb_s[512];    // bf16(s), 1 KB
    int bh = blockIdx.x;
    int n = bh >> 3;
    int tid = threadIdx.x, lane = tid & 63, w = tid >> 6;

    {
        int p = tid >> 2, q = tid & 3;
        uint4 wds = *(const uint4*)(bitsT + ((size_t)(n * 256 + p)) * 16 + q * 4);
        bT_s[(q * 4 + 0) * 256 + p] = wds.x;
        bT_s[(q * 4 + 1) * 256 + p] = wds.y;
        bT_s[(q * 4 + 2) * 256 + p] = wds.z;
        bT_s[(q * 4 + 3) * 256 + p] = wds.w;
    }
    if (tid < 512) smb_s[tid] = s_in[(size_t)bh * 512 + tid];
    {
        const unsigned short* xb = xhb + (size_t)bh * 65536;
        #pragma unroll
        for (int rep = 0; rep < 8; ++rep) {
            int idx = rep * 1024 + tid;
            *(short8*)&kpk[idx * 8] = *(const short8*)(xb + (size_t)idx * 8);
        }
    }
    __syncthreads();

    int rl = lane & 15, g = lane >> 4;
    int wm = w & 7, wn = w >> 3;
    f32x4 acc[2][4];
    #pragma unroll
    for (int i = 0; i < 2; ++i)
        #pragma unroll
        for (int nt = 0; nt < 4; ++nt) acc[i][nt] = (f32x4){0.f, 0.f, 0.f, 0.f};

    for (int kt = 0; kt < 16; ++kt) {
        short8 sv = *(const short8*)&smb_s[kt * 32 + g * 8];
        short8 bfr[4];
        #pragma unroll
        for (int nt = 0; nt < 4; ++nt)
            bfr[nt] = *(const short8*)&kpk[(((kt * 4 + g) << 7) + wn * 64 + nt * 16 + rl) * 8];
        #pragma unroll
        for (int i = 0; i < 2; ++i) {
            unsigned word = bT_s[kt * 256 + (wm * 2 + i) * 16 + rl];
            unsigned byte = (word >> (g * 8)) & 255u;
            short8 af;
            #pragma unroll
            for (int j = 0; j < 8; ++j)
                af[j] = ((byte >> j) & 1u) ? sv[j] : (short)0x3E00;
            #pragma unroll
            for (int nt = 0; nt < 4; ++nt)
                acc[i][nt] = __builtin_amdgcn_mfma_f32_16x16x32_bf16(af, bfr[nt], acc[i][nt], 0, 0, 0);
        }
    }

    float* ob = heg + (size_t)bh * (PP * EE);
    #pragma unroll
    for (int i = 0; i < 2; ++i)
        #pragma unroll
        for (int nt = 0; nt < 4; ++nt) {
            int e = wn * 64 + nt * 16 + rl;
            #pragma unroll
            for (int r = 0; r < 4; ++r) {
                int p = (wm * 2 + i) * 16 + g * 4 + r;
                ob[(size_t)p * 128 + e] = gelu_f(acc[i][nt][r]);
            }
        }
}

// ---------------- gemm3: he = heg@W3+b3 in-register (K-half staged); fused ev + heT bf16 transpose
__global__ __launch_bounds__(256) void gemm3(const float* __restrict__ A,
                                             const unsigned short* __restrict__ Bhi,
                                             const unsigned short* __restrict__ Blo,
                                             const float* __restrict__ bias,
                                             const float* __restrict__ W4,
                                             unsigned short* __restrict__ heT,
                                             float* __restrict__ ev) {
    __shared__ __align__(16) char buf[32768];   // As half (32 KB) then tbuf (32 KB)
    __shared__ float rs_ae[128];
    float* As = (float*)buf;
    unsigned short* tbuf = (unsigned short*)buf;
    int tid = threadIdx.x, lane = tid & 63, w = tid >> 6;
    size_t blockRow0 = (size_t)blockIdx.x * 128;
    int rl = lane & 15, g = lane >> 4;

    f32x4 acc[2][8];
    #pragma unroll
    for (int t = 0; t < 2; ++t)
        #pragma unroll
        for (int nt = 0; nt < 8; ++nt) acc[t][nt] = (f32x4){0.f, 0.f, 0.f, 0.f};

    #pragma unroll
    for (int kh = 0; kh < 2; ++kh) {
        if (kh) __syncthreads();
        {
            const float* Ag = A + blockRow0 * 128 + kh * 64;
            #pragma unroll
            for (int i = 0; i < 8; ++i) {
                int idx = i * 256 + tid;
                int row = idx >> 4, c4 = idx & 15;
                f32x4 v = *(const f32x4*)(Ag + (size_t)row * 128 + c4 * 4);
                *(f32x4*)((char*)As + ((row * 256 + c4 * 16) ^ ((row & 7) << 5))) = v;
            }
        }
        __syncthreads();
        #pragma unroll
        for (int kcl = 0; kcl < 2; ++kcl) {
            int kc = kh * 2 + kcl;
            short8 ah[2], al[2];
            #pragma unroll
            for (int t = 0; t < 2; ++t) {
                int arow = w * 32 + t * 16 + rl;
                int cb = (kcl * 32 + g * 8) * 4;
                int sw = (arow & 7) << 5;
                f32x4 a0 = *(const f32x4*)((char*)As + ((arow * 256 + cb) ^ sw));
                f32x4 a1 = *(const f32x4*)((char*)As + ((arow * 256 + cb + 16) ^ sw));
                float av[8] = {a0.x, a0.y, a0.z, a0.w, a1.x, a1.y, a1.z, a1.w};
                #pragma unroll
                for (int j = 0; j < 8; ++j) {
                    unsigned short hb = bf16_rne(av[j]);
                    float hf = __uint_as_float((unsigned)hb << 16);
                    ah[t][j] = (short)hb;
                    al[t][j] = (short)bf16_rne(av[j] - hf);
                }
            }
            #pragma unroll
            for (int nt = 0; nt < 8; ++nt) {
                int oct = kc * 4 + g, col = nt * 16 + rl;
                short8 bh = *(const short8*)(Bhi + ((size_t)(oct * 128 + col)) * 8);
                short8 bl = *(const short8*)(Blo + ((size_t)(oct * 128 + col)) * 8);
                #pragma unroll
                for (int t = 0; t < 2; ++t) {
                    acc[t][nt] = __builtin_amdgcn_mfma_f32_16x16x32_bf16(ah[t], bh, acc[t][nt], 0, 0, 0);
                    acc[t][nt] = __builtin_amdgcn_mfma_f32_16x16x32_bf16(ah[t], bl, acc[t][nt], 0, 0, 0);
                    acc[t][nt] = __builtin_amdgcn_mfma_f32_16x16x32_bf16(al[t], bh, acc[t][nt], 0, 0, 0);
                }
            }
        }
    }
    __syncthreads();   // As dead; buf becomes tbuf

    float ae_p[2][4] = {{0.f,0.f,0.f,0.f},{0.f,0.f,0.f,0.f}};
    #pragma unroll
    for (int nt = 0; nt < 8; ++nt) {
        int col = nt * 16 + rl;
        float bv = bias[col], w4v = W4[col];
        #pragma unroll
        for (int t = 0; t < 2; ++t) {
            float v0 = acc[t][nt][0] + bv;
            float v1 = acc[t][nt][1] + bv;
            float v2 = acc[t][nt][2] + bv;
            float v3 = acc[t][nt][3] + bv;
            ae_p[t][0] += gelu_f(v0) * w4v;
            ae_p[t][1] += gelu_f(v1) * w4v;
            ae_p[t][2] += gelu_f(v2) * w4v;
            ae_p[t][3] += gelu_f(v3) * w4v;
            int row_loc = w * 32 + t * 16 + g * 4;
            int byte = (col * 256 + row_loc * 2) ^ ((col & 7) << 4);
            *(ushort4*)((char*)tbuf + byte) =
                make_ushort4(bf16_rne(v0), bf16_rne(v1), bf16_rne(v2), bf16_rne(v3));
        }
    }
    #pragma unroll
    for (int t = 0; t < 2; ++t)
        #pragma unroll
        for (int r = 0; r < 4; ++r) {
            float a = ae_p[t][r];
            a += __shfl_xor(a, 1); a += __shfl_xor(a, 2); a += __shfl_xor(a, 4); a += __shfl_xor(a, 8);
            if (rl == 0) rs_ae[w * 32 + t * 16 + g * 4 + r] = a;
        }
    __syncthreads();
    int bh2 = blockIdx.x >> 1, p0 = (blockIdx.x & 1) * 128;
    #pragma unroll
    for (int rep = 0; rep < 8; ++rep) {
        int id = rep * 256 + tid;
        int e = id >> 4, j = id & 15;
        int byte = (e * 256 + j * 16) ^ ((e & 7) << 4);
        short8 v = *(const short8*)((char*)tbuf + byte);
        *(short8*)(heT + (size_t)bh2 * 32768 + (size_t)e * 256 + p0 + j * 8) = v;
    }
    if (tid < 128) {
        int row = blockIdx.x * 128 + tid;
        int n = row >> 11, h = (row >> 8) & 7, p = row & 255;
        ev[((size_t)(n * 256 + p)) * 8 + h] = expf(rs_ae[tid]);
    }
}

// ---------------- k4_dense: rdm[n][l][p] = bit ? 1/den : 0  (bf16, h-shared)
__global__ __launch_bounds__(256) void k4_dense(const float* __restrict__ eu,
                                                const float* __restrict__ ev,
                                                const unsigned* __restrict__ bits,
                                                unsigned short* __restrict__ rdm) {
    __shared__ float ev_t[256][8];
    int b = blockIdx.x;
    int n = b >> 3, l0 = (b & 7) * 64;
    int tid = threadIdx.x;
    {
        const f32x4* src = (const f32x4*)(ev + (size_t)n * 2048);
        f32x4* dst = (f32x4*)&ev_t[0][0];
        dst[tid] = src[tid];
        dst[tid + 256] = src[tid + 256];
    }
    __syncthreads();
    int l = l0 + (tid >> 2), pq = tid & 3;
    size_t rowg = (size_t)n * 512 + l;
    f32x4 ea = *(const f32x4*)(eu + rowg * 8);
    f32x4 eb = *(const f32x4*)(eu + rowg * 8 + 4);
    unsigned w0 = bits[rowg * 8 + pq * 2], w1 = bits[rowg * 8 + pq * 2 + 1];
    for (int c = 0; c < 8; ++c) {
        short8 o8;
        #pragma unroll
        for (int k = 0; k < 8; ++k) {
            int pl = c * 8 + k;
            int p = pq * 64 + pl;
            f32x4 va = *(const f32x4*)&ev_t[p][0];
            f32x4 vb = *(const f32x4*)&ev_t[p][4];
            float den = ea.x * va.x + ea.y * va.y + ea.z * va.z + ea.w * va.w
                      + eb.x * vb.x + eb.y * vb.y + eb.z * vb.z + eb.w * vb.w;
            unsigned bit = (pl < 32) ? ((w0 >> pl) & 1u) : ((w1 >> (pl - 32)) & 1u);
            float r = bit ? rcp_f(den) : 0.0f;
            o8[k] = (short)bf16_rne(r);
        }
        *(short8*)(rdm + rowg * 256 + pq * 64 + c * 8) = o8;
    }
}

// ---------------- k5_mfma: x_nodes = 0.125*colsum(he) + A @ he; 1024 threads (16 waves)
__global__ __launch_bounds__(1024) void k5_mfma(const unsigned short* __restrict__ heT,
                                                const unsigned short* __restrict__ rdm,
                                                const float* __restrict__ eu,
                                                const float* __restrict__ ev,
                                                const unsigned* __restrict__ flags,
                                                const float* __restrict__ x,
                                                float* __restrict__ out) {
    __shared__ __align__(16) unsigned short heT_s[128 * 256];  // swizzled [e][p], 64 KB
    __shared__ __align__(16) unsigned short A_s[64 * 256];     // swizzled [l_loc][p], 32 KB
    __shared__ float evh_s[256];
    __shared__ float euh_s[64];
    __shared__ float cs_s[128];
    __shared__ float csr_s[4][128];
    __shared__ unsigned flg_s[64];

    int bid = blockIdx.x;
    int xcd = bid & 7, slot = bid >> 3;          // group 8 heads of same n per XCD (rdm L2 reuse)
    int n = xcd * 4 + (slot & 3), h = slot >> 2;
    int bh = n * 8 + h;
    int tid = threadIdx.x, lane = tid & 63, w = tid >> 6;

    const unsigned short* hb = heT + (size_t)bh * 32768;
    #pragma unroll
    for (int i = 0; i < 4; ++i) {
        int id = tid + i * 1024;
        int e = id >> 5, jj = id & 31;
        short8 v = *(const short8*)(hb + e * 256 + jj * 8);
        *(short8*)((char*)heT_s + ((e * 512 + jj * 16) ^ ((e & 7) << 4))) = v;
    }
    if (tid < 256) evh_s[tid] = ev[((size_t)(n * 256 + tid)) * 8 + h];
    __syncthreads();
    if (tid < 512) {
        int e = tid & 127, q = tid >> 7;
        float a = 0.f;
        #pragma unroll
        for (int j = 0; j < 8; ++j) {
            int byte = (e * 512 + (q * 64 + j * 8) * 2) ^ ((e & 7) << 4);
            short8 v = *(const short8*)((char*)heT_s + byte);
            #pragma unroll
            for (int k = 0; k < 8; ++k) a += bf2f(v[k]);
        }
        csr_s[q][e] = a;
    }
    __syncthreads();
    if (tid < 128) cs_s[tid] = 0.125f * (csr_s[0][tid] + csr_s[1][tid] + csr_s[2][tid] + csr_s[3][tid]);

    int rl = lane & 15, g = lane >> 4;
    int wm = w & 3, wn = w >> 2;       // 4 mt x 4 e-groups (2 nt each)
    int swz = (rl & 7) << 4;

    for (int lt = 0; lt < 8; ++lt) {
        int l0 = lt * 64;
        if (tid < 64) {
            euh_s[tid] = eu[((size_t)(n * 512 + l0 + tid)) * 8 + h];
            flg_s[tid] = flags[n * 512 + l0 + tid];
        }
        __syncthreads();
        {
            int l_loc = tid >> 4, p8 = (tid & 15) * 16;
            float euh = euh_s[l_loc];
            const unsigned short* rp = rdm + ((size_t)(n * 512 + l0 + l_loc)) * 256 + p8;
            #pragma unroll
            for (int c = 0; c < 2; ++c) {
                short8 rv = *(const short8*)(rp + c * 8);
                short8 o8;
                #pragma unroll
                for (int k = 0; k < 8; ++k) {
                    unsigned u = (unsigned)(unsigned short)rv[k];
                    float rf = __uint_as_float(u << 16);
                    float m125 = (u != 0u) ? -0.125f : 0.0f;
                    float a = fmaf(euh * evh_s[p8 + c * 8 + k], rf, m125);
                    o8[k] = (short)bf16_rne(a);
                }
                *(short8*)((char*)A_s + ((l_loc * 512 + (p8 + c * 8) * 2) ^ ((l_loc & 7) << 4))) = o8;
            }
        }
        __syncthreads();
        f32x4 acc[2];
        acc[0] = (f32x4){0.f, 0.f, 0.f, 0.f};
        acc[1] = (f32x4){0.f, 0.f, 0.f, 0.f};
        #pragma unroll
        for (int kt = 0; kt < 8; ++kt) {
            int arow = wm * 16 + rl;
            short8 af = *(const short8*)((char*)A_s + ((arow * 512 + kt * 64 + g * 16) ^ swz));
            short8 b0, b1;
            {
                int e0 = wn * 32 + rl;
                int e1 = wn * 32 + 16 + rl;
                b0 = *(const short8*)((char*)heT_s + ((e0 * 512 + kt * 64 + g * 16) ^ swz));
                b1 = *(const short8*)((char*)heT_s + ((e1 * 512 + kt * 64 + g * 16) ^ swz));
            }
            acc[0] = __builtin_amdgcn_mfma_f32_16x16x32_bf16(af, b0, acc[0], 0, 0, 0);
            acc[1] = __builtin_amdgcn_mfma_f32_16x16x32_bf16(af, b1, acc[1], 0, 0, 0);
        }
        #pragma unroll
        for (int j = 0; j < 2; ++j) {
            int e = wn * 32 + j * 16 + rl;
            float csv = cs_s[e];
            #pragma unroll
            for (int r = 0; r < 4; ++r) {
                int row = wm * 16 + g * 4 + r;
                int l = l0 + row;
                size_t addr = ((size_t)(n * 512 + l)) * 1024 + h * 128 + e;
                if (flg_s[row]) {
                    out[addr] = x[addr];
                } else {
                    out[addr] = gelu_f(acc[j][r] + csv);
                }
            }
        }
        __syncthreads();
    }
}

extern "C" void kernel_launch(void* const* d_in, const int* in_sizes, int n_in,
                              void* d_out, int out_size, void* d_ws, size_t ws_size,
                              hipStream_t stream) {
    (void)in_sizes; (void)n_in; (void)out_size; (void)ws_size;
    const float* x   = (const float*)d_in[0];
    const float* adj = (const float*)d_in[1];
    const float* W1  = (const float*)d_in[2];
    const float* b1  = (const float*)d_in[3];
    const float* W2  = (const float*)d_in[4];
    const float* W3  = (const float*)d_in[6];
    const float* b3  = (const float*)d_in[7];
    const float* W4  = (const float*)d_in[8];
    float* out = (float*)d_out;

    char* ws = (char*)d_ws;
    size_t off = 0;
    auto alloc = [&](size_t bytes) -> void* {
        void* p = ws + off;
        off += (bytes + 255) & ~(size_t)255;
        return p;
    };
    unsigned short* xhb = (unsigned short*)alloc((size_t)NB * HH * 65536 * 2);   // 33.5 MB bf16 k-packed
    unsigned short* sb  = (unsigned short*)alloc((size_t)NB * HH * LL * 2);      // bf16 s
    float* eu   = (float*)alloc((size_t)NB * LL * HH * 4);
    float* ev   = (float*)alloc((size_t)NB * PP * HH * 4);
    float* heg  = (float*)alloc((size_t)NB * HH * PP * EE * 4);                  // 33.5 MB
    unsigned short* heT = (unsigned short*)alloc((size_t)NB * HH * EE * PP * 2); // 16.8 MB [(n,h)][e][p]
    unsigned short* rdm = (unsigned short*)alloc((size_t)NB * LL * PP * 2);      // 8.4 MB [n][l][p]
    unsigned* bits  = (unsigned*)alloc((size_t)NB * LL * 8 * 4);
    unsigned* bitsT = (unsigned*)alloc((size_t)NB * PP * 16 * 4);
    unsigned* flags = (unsigned*)alloc((size_t)NB * LL * 4);
    unsigned short* W1h = (unsigned short*)alloc(16384 * 2);
    unsigned short* W1l = (unsigned short*)alloc(16384 * 2);
    unsigned short* W3h = (unsigned short*)alloc(16384 * 2);
    unsigned short* W3l = (unsigned short*)alloc(16384 * 2);

    hipLaunchKernelGGL(kpack, dim3(2), dim3(256), 0, stream, W1, W3, W1h, W1l, W3h, W3l);
    hipLaunchKernelGGL(k0_bits, dim3(NB * 8), dim3(256), 0, stream, adj, bits, bitsT, flags);
    hipLaunchKernelGGL(gemm1c, dim3(1024), dim3(1024), 0, stream, x, W1h, W1l, b1, W2, W4, xhb, sb, eu);
    hipLaunchKernelGGL(k2_mfma, dim3(NB * HH), dim3(1024), 0, stream, xhb, sb, bitsT, heg);
    hipLaunchKernelGGL(gemm3, dim3(512), dim3(256), 0, stream, heg, W3h, W3l, b3, W4, heT, ev);
    hipLaunchKernelGGL(k4_dense, dim3(NB * 8), dim3(256), 0, stream, eu, ev, bits, rdm);
    hipLaunchKernelGGL(k5_mfma, dim3(NB * HH), dim3(1024), 0, stream, heT, rdm, eu, ev, flags, x, out);
}

// Round 14
// 174.645 us; speedup vs baseline: 1.5628x; 1.1934x over previous
//
#include <hip/hip_runtime.h>
#include <math.h>

#define NB 32
#define LL 512
#define PP 256
#define HH 8
#define EE 128
#define DD 1024

typedef __attribute__((ext_vector_type(4))) float f32x4;
typedef __attribute__((ext_vector_type(8))) short short8;

__device__ __forceinline__ float gelu_f(float v) {
    return 0.5f * v * (1.0f + erff(v * 0.70710678118654752f));
}
__device__ __forceinline__ float rcp_f(float v) {
    float r; asm("v_rcp_f32 %0, %1" : "=v"(r) : "v"(v)); return r;
}
__device__ __forceinline__ unsigned short bf16_rne(float v) {
    unsigned u = __float_as_uint(v);
    unsigned r = u + 0x7FFFu + ((u >> 16) & 1u);
    return (unsigned short)(r >> 16);
}
__device__ __forceinline__ float bf2f(short s) {
    return __uint_as_float(((unsigned)(unsigned short)s) << 16);
}

// ---------------- kpack: W (128x128 fp32) -> bf16 hi/lo in MFMA B-fragment order
__global__ __launch_bounds__(256) void kpack(const float* __restrict__ W1,
                                             const float* __restrict__ W3,
                                             unsigned short* __restrict__ W1h,
                                             unsigned short* __restrict__ W1l,
                                             unsigned short* __restrict__ W3h,
                                             unsigned short* __restrict__ W3l) {
    const float* W = blockIdx.x ? W3 : W1;
    unsigned short* Ph = blockIdx.x ? W3h : W1h;
    unsigned short* Pl = blockIdx.x ? W3l : W1l;
    for (int i = threadIdx.x; i < 16384; i += 256) {
        int oct = i >> 10, col = (i >> 3) & 127, j = i & 7;
        float v = W[(oct * 8 + j) * 128 + col];
        unsigned short hb = bf16_rne(v);
        float hf = __uint_as_float((unsigned)hb << 16);
        Ph[i] = hb;
        Pl[i] = bf16_rne(v - hf);
    }
}

// ---------------- K0: pack mask to bits (row-major + col-major) + no-edge flags
__global__ __launch_bounds__(256) void k0_bits(const float* __restrict__ adj,
                                               unsigned* __restrict__ bits,
                                               unsigned* __restrict__ bitsT,
                                               unsigned* __restrict__ flags) {
    __shared__ unsigned lbits[64][8];
    int n  = blockIdx.x >> 3;
    int l0 = (blockIdx.x & 7) * 64;
    int lane = threadIdx.x & 63;
    int wv   = threadIdx.x >> 6;
    for (int r = wv; r < 64; r += 4) {
        int l = l0 + r;
        const float* row = adj + ((size_t)n * LL + l) * PP;
        int cnt = 0;
        for (int c = 0; c < 4; ++c) {
            float v = row[c * 64 + lane];
            unsigned long long b = __ballot(v != 0.0f);
            if (lane == 0) {
                lbits[r][c * 2]     = (unsigned)b;
                lbits[r][c * 2 + 1] = (unsigned)(b >> 32);
                cnt += __popcll(b);
            }
        }
        if (lane == 0) {
            flags[n * LL + l] = (cnt == 0) ? 1u : 0u;
            for (int w = 0; w < 8; ++w)
                bits[((size_t)n * LL + l) * 8 + w] = lbits[r][w];
        }
    }
    __syncthreads();
    int p = threadIdx.x;
    unsigned w0 = 0, w1 = 0;
    int wp = p >> 5, bp = p & 31;
    for (int j = 0; j < 32; ++j) {
        w0 |= ((lbits[j][wp] >> bp) & 1u) << j;
        w1 |= ((lbits[j + 32][wp] >> bp) & 1u) << j;
    }
    bitsT[((size_t)n * PP + p) * 16 + (l0 >> 5)]     = w0;
    bitsT[((size_t)n * PP + p) * 16 + (l0 >> 5) + 1] = w1;
}

// ---------------- gemm1c: xh = x@W1+b1; 1024 thr / 16 waves; tbuf [l_loc][e][h] bf16
__global__ __launch_bounds__(1024) void gemm1c(const float* __restrict__ A,
                                               const unsigned short* __restrict__ Bhi,
                                               const unsigned short* __restrict__ Blo,
                                               const float* __restrict__ bias,
                                               const float* __restrict__ W2,
                                               const float* __restrict__ W4,
                                               unsigned short* __restrict__ xhb,
                                               unsigned short* __restrict__ sb,
                                               float* __restrict__ eu) {
    __shared__ __align__(16) char buf[32768];   // As half (32 KB) then tbuf (32 KB)
    __shared__ float rs4[4][128][2];
    __shared__ float rs[128][2];
    float* As = (float*)buf;
    unsigned short* tbuf = (unsigned short*)buf;
    int tid = threadIdx.x, lane = tid & 63, w = tid >> 6;
    int b = blockIdx.x;
    size_t blockRow0 = (size_t)b * 128;
    int rl = lane & 15, g = lane >> 4;
    int mt = w & 7, eh = w >> 3;

    f32x4 acc[4];
    #pragma unroll
    for (int nt = 0; nt < 4; ++nt) acc[nt] = (f32x4){0.f, 0.f, 0.f, 0.f};

    #pragma unroll
    for (int kh = 0; kh < 2; ++kh) {
        if (kh) __syncthreads();
        {   // stage 128 rows x 64 cols fp32, coalesced, row-swizzled
            const float* Ag = A + blockRow0 * 128 + kh * 64;
            #pragma unroll
            for (int i = 0; i < 2; ++i) {
                int idx = i * 1024 + tid;
                int row = idx >> 4, c4 = idx & 15;
                f32x4 v = *(const f32x4*)(Ag + (size_t)row * 128 + c4 * 4);
                *(f32x4*)((char*)As + ((row * 256 + c4 * 16) ^ ((row & 7) << 5))) = v;
            }
        }
        __syncthreads();
        #pragma unroll
        for (int kcl = 0; kcl < 2; ++kcl) {
            int kc = kh * 2 + kcl;
            short8 ah, al;
            {
                int arow = mt * 16 + rl;
                int cb = (kcl * 32 + g * 8) * 4;
                int sw = (arow & 7) << 5;
                f32x4 a0 = *(const f32x4*)((char*)As + ((arow * 256 + cb) ^ sw));
                f32x4 a1 = *(const f32x4*)((char*)As + ((arow * 256 + cb + 16) ^ sw));
                float av[8] = {a0.x, a0.y, a0.z, a0.w, a1.x, a1.y, a1.z, a1.w};
                #pragma unroll
                for (int j = 0; j < 8; ++j) {
                    unsigned short hb = bf16_rne(av[j]);
                    float hf = __uint_as_float((unsigned)hb << 16);
                    ah[j] = (short)hb;
                    al[j] = (short)bf16_rne(av[j] - hf);
                }
            }
            #pragma unroll
            for (int ntl = 0; ntl < 4; ++ntl) {
                int oct = kc * 4 + g, col = eh * 64 + ntl * 16 + rl;
                short8 bh = *(const short8*)(Bhi + ((size_t)(oct * 128 + col)) * 8);
                short8 bl = *(const short8*)(Blo + ((size_t)(oct * 128 + col)) * 8);
                acc[ntl] = __builtin_amdgcn_mfma_f32_16x16x32_bf16(ah, bh, acc[ntl], 0, 0, 0);
                acc[ntl] = __builtin_amdgcn_mfma_f32_16x16x32_bf16(ah, bl, acc[ntl], 0, 0, 0);
                acc[ntl] = __builtin_amdgcn_mfma_f32_16x16x32_bf16(al, bh, acc[ntl], 0, 0, 0);
            }
        }
    }
    __syncthreads();   // As dead; buf becomes tbuf

    // Phase B: acc -> tbuf[l_loc][e][h], ushort4 (4 consecutive h), conflict-free
    {
        int l_loc = mt * 2 + (g >> 1);
        int hbase2 = (g & 1) * 8;
        #pragma unroll
        for (int ntl = 0; ntl < 4; ++ntl) {
            int col = eh * 64 + ntl * 16 + rl;
            float bv = bias[col];
            ushort4 o;
            o.x = bf16_rne(acc[ntl][0] + bv);
            o.y = bf16_rne(acc[ntl][1] + bv);
            o.z = bf16_rne(acc[ntl][2] + bv);
            o.w = bf16_rne(acc[ntl][3] + bv);
            *(ushort4*)((char*)tbuf + (l_loc * 2048 + col * 16 + hbase2)) = o;
        }
    }
    __syncthreads();

    // Phase C: per-row gelu sums; thread = (eq, l_loc, ec)
    {
        int ec = tid & 15, l_loc = (tid >> 4) & 15, eq = tid >> 8;
        float xv_p[8] = {0,0,0,0,0,0,0,0};
        float an_p[8] = {0,0,0,0,0,0,0,0};
        #pragma unroll
        for (int i = 0; i < 2; ++i) {
            int e = (eq * 2 + i) * 16 + ec;
            short8 v = *(const short8*)((char*)tbuf + (l_loc * 2048 + e * 16));
            float w2 = W2[e], w4 = W4[128 + e];
            #pragma unroll
            for (int h = 0; h < 8; ++h) {
                float gv = gelu_f(bf2f(v[h]));
                xv_p[h] += gv * w2;
                an_p[h] += gv * w4;
            }
        }
        #pragma unroll
        for (int h = 0; h < 8; ++h) {
            #pragma unroll
            for (int m = 1; m < 16; m <<= 1) {
                xv_p[h] += __shfl_xor(xv_p[h], m);
                an_p[h] += __shfl_xor(an_p[h], m);
            }
        }
        if (ec == 0) {
            #pragma unroll
            for (int h = 0; h < 8; ++h) {
                rs4[eq][l_loc * 8 + h][0] = xv_p[h];
                rs4[eq][l_loc * 8 + h][1] = an_p[h];
            }
        }
    }

    // Phase D: tbuf -> xhb k-packed
    int n = b >> 5, kg0 = (b & 31) * 2;
    #pragma unroll
    for (int rep = 0; rep < 2; ++rep) {
        int id = rep * 1024 + tid;
        int h = (id >> 8) & 7, kg = (id >> 7) & 1, e = id & 127;
        short8 v;
        #pragma unroll
        for (int j = 0; j < 8; ++j)
            v[j] = (short)*(const unsigned short*)((char*)tbuf + ((kg * 8 + j) * 2048 + e * 16 + h * 2));
        *(short8*)(xhb + ((size_t)(n * 8 + h)) * 65536 + (size_t)((kg0 + kg) * 128 + e) * 8) = v;
    }
    __syncthreads();

    if (tid < 128) {
        rs[tid][0] = rs4[0][tid][0] + rs4[1][tid][0] + rs4[2][tid][0] + rs4[3][tid][0];
        rs[tid][1] = rs4[0][tid][1] + rs4[1][tid][1] + rs4[2][tid][1] + rs4[3][tid][1];
    }
    __syncthreads();
    if (tid < 16) {
        int l = (b & 31) * 16 + tid;
        float xv[8], an[8];
        #pragma unroll
        for (int h = 0; h < 8; ++h) { xv[h] = rs[tid * 8 + h][0]; an[h] = rs[tid * 8 + h][1]; }
        float mx = xv[0];
        #pragma unroll
        for (int h = 1; h < 8; ++h) mx = fmaxf(mx, xv[h]);
        float ex[8], ssum = 0.f;
        #pragma unroll
        for (int h = 0; h < 8; ++h) { ex[h] = expf(xv[h] - mx); ssum += ex[h]; }
        float inv = 1.0f / ssum;
        #pragma unroll
        for (int h = 0; h < 8; ++h)
            sb[((size_t)(n * 8 + h)) * 512 + l] = bf16_rne(ex[h] * inv);
        float mxa = an[0];
        #pragma unroll
        for (int h = 1; h < 8; ++h) mxa = fmaxf(mxa, an[h]);
        f32x4 e0, e1;
        #pragma unroll
        for (int h = 0; h < 4; ++h) e0[h] = expf(an[h] - mxa);
        #pragma unroll
        for (int h = 0; h < 4; ++h) e1[h] = expf(an[4 + h] - mxa);
        float* ep = eu + ((size_t)(n * 512 + l)) * 8;
        *(f32x4*)ep = e0;
        *(f32x4*)(ep + 4) = e1;
    }
}

// ---------------- k23_fused: stage1 heg = gelu(A'@xh) (LDS bf16) ; stage2 he = heg@W3+b3
// -> heT bf16 transpose out + ev. heg never touches HBM.
__global__ __launch_bounds__(1024) void k23_fused(const unsigned short* __restrict__ xhb,
                                                  const unsigned short* __restrict__ s_in,
                                                  const unsigned* __restrict__ bitsT,
                                                  const unsigned short* __restrict__ W3h,
                                                  const unsigned short* __restrict__ W3l,
                                                  const float* __restrict__ b3,
                                                  const float* __restrict__ W4,
                                                  unsigned short* __restrict__ heT,
                                                  float* __restrict__ ev) {
    __shared__ __align__(16) unsigned short kpk[65536];    // 128 KB; after stage1: A2 (64KB) | tbuf (64KB)
    __shared__ unsigned bT_s[16 * 256];                    // 16 KB
    __shared__ __align__(16) unsigned short smb_s[512];    // 1 KB
    __shared__ float rs_ae[256][2];                        // 2 KB
    int bh = blockIdx.x;
    int n = bh >> 3, h = bh & 7;
    int tid = threadIdx.x, lane = tid & 63, w = tid >> 6;
    int rl = lane & 15, g = lane >> 4;

    {
        int p = tid >> 2, q = tid & 3;
        uint4 wds = *(const uint4*)(bitsT + ((size_t)(n * 256 + p)) * 16 + q * 4);
        bT_s[(q * 4 + 0) * 256 + p] = wds.x;
        bT_s[(q * 4 + 1) * 256 + p] = wds.y;
        bT_s[(q * 4 + 2) * 256 + p] = wds.z;
        bT_s[(q * 4 + 3) * 256 + p] = wds.w;
    }
    if (tid < 512) smb_s[tid] = s_in[(size_t)bh * 512 + tid];
    {
        const unsigned short* xb = xhb + (size_t)bh * 65536;
        #pragma unroll
        for (int rep = 0; rep < 8; ++rep) {
            int idx = rep * 1024 + tid;
            *(short8*)&kpk[idx * 8] = *(const short8*)(xb + (size_t)idx * 8);
        }
    }
    __syncthreads();

    // ---- stage 1: heg[p][e] = A' @ xh (acc in regs)
    int wm = w & 7, wn = w >> 3;
    f32x4 acc[2][4];
    #pragma unroll
    for (int i = 0; i < 2; ++i)
        #pragma unroll
        for (int nt = 0; nt < 4; ++nt) acc[i][nt] = (f32x4){0.f, 0.f, 0.f, 0.f};

    for (int kt = 0; kt < 16; ++kt) {
        short8 sv = *(const short8*)&smb_s[kt * 32 + g * 8];
        short8 bfr[4];
        #pragma unroll
        for (int nt = 0; nt < 4; ++nt)
            bfr[nt] = *(const short8*)&kpk[(((kt * 4 + g) << 7) + wn * 64 + nt * 16 + rl) * 8];
        #pragma unroll
        for (int i = 0; i < 2; ++i) {
            unsigned word = bT_s[kt * 256 + (wm * 2 + i) * 16 + rl];
            unsigned byte = (word >> (g * 8)) & 255u;
            short8 af;
            #pragma unroll
            for (int j = 0; j < 8; ++j)
                af[j] = ((byte >> j) & 1u) ? sv[j] : (short)0x3E00;
            #pragma unroll
            for (int nt = 0; nt < 4; ++nt)
                acc[i][nt] = __builtin_amdgcn_mfma_f32_16x16x32_bf16(af, bfr[nt], acc[i][nt], 0, 0, 0);
        }
    }
    __syncthreads();   // all waves done reading kpk; reuse as A2 | tbuf

    char* A2  = (char*)kpk;           // A2[p][e] bf16, row 256B, swz ^((p&15)<<4)
    char* tb2 = (char*)kpk + 65536;   // tbuf he[f][p] bf16, row 512B, swz ^((f&7)<<4)

    #pragma unroll
    for (int i = 0; i < 2; ++i)
        #pragma unroll
        for (int nt = 0; nt < 4; ++nt) {
            int e = wn * 64 + nt * 16 + rl;
            #pragma unroll
            for (int r = 0; r < 4; ++r) {
                int p = (wm * 2 + i) * 16 + g * 4 + r;
                *(unsigned short*)(A2 + ((p * 256 + e * 2) ^ ((p & 15) << 4))) =
                    bf16_rne(gelu_f(acc[i][nt][r]));
            }
        }
    __syncthreads();

    // ---- stage 2: he[p][f] = A2 @ (W3h + W3l) + b3
    f32x4 acc2[2][4];
    #pragma unroll
    for (int i = 0; i < 2; ++i)
        #pragma unroll
        for (int nt = 0; nt < 4; ++nt) acc2[i][nt] = (f32x4){0.f, 0.f, 0.f, 0.f};

    #pragma unroll
    for (int kt2 = 0; kt2 < 4; ++kt2) {
        short8 af2[2];
        #pragma unroll
        for (int i = 0; i < 2; ++i) {
            int p = (wm * 2 + i) * 16 + rl;
            af2[i] = *(const short8*)(A2 + ((p * 256 + (kt2 * 32 + g * 8) * 2) ^ ((p & 15) << 4)));
        }
        #pragma unroll
        for (int nt = 0; nt < 4; ++nt) {
            int oct = kt2 * 4 + g, col = (wn * 4 + nt) * 16 + rl;
            short8 bhv = *(const short8*)(W3h + ((size_t)(oct * 128 + col)) * 8);
            short8 blv = *(const short8*)(W3l + ((size_t)(oct * 128 + col)) * 8);
            #pragma unroll
            for (int i = 0; i < 2; ++i) {
                acc2[i][nt] = __builtin_amdgcn_mfma_f32_16x16x32_bf16(af2[i], bhv, acc2[i][nt], 0, 0, 0);
                acc2[i][nt] = __builtin_amdgcn_mfma_f32_16x16x32_bf16(af2[i], blv, acc2[i][nt], 0, 0, 0);
            }
        }
    }

    // ---- epilogue: bias, ae partials, he -> tbuf (transposed)
    float ae_p[2][4] = {{0.f,0.f,0.f,0.f},{0.f,0.f,0.f,0.f}};
    #pragma unroll
    for (int nt = 0; nt < 4; ++nt) {
        int f = (wn * 4 + nt) * 16 + rl;
        float bv = b3[f], w4v = W4[f];
        #pragma unroll
        for (int i = 0; i < 2; ++i) {
            float v0 = acc2[i][nt][0] + bv;
            float v1 = acc2[i][nt][1] + bv;
            float v2 = acc2[i][nt][2] + bv;
            float v3 = acc2[i][nt][3] + bv;
            ae_p[i][0] += gelu_f(v0) * w4v;
            ae_p[i][1] += gelu_f(v1) * w4v;
            ae_p[i][2] += gelu_f(v2) * w4v;
            ae_p[i][3] += gelu_f(v3) * w4v;
            int p0 = (wm * 2 + i) * 16 + g * 4;
            int byte = (f * 512 + p0 * 2) ^ ((f & 7) << 4);
            *(ushort4*)(tb2 + byte) =
                make_ushort4(bf16_rne(v0), bf16_rne(v1), bf16_rne(v2), bf16_rne(v3));
        }
    }
    #pragma unroll
    for (int i = 0; i < 2; ++i)
        #pragma unroll
        for (int r = 0; r < 4; ++r) {
            float a = ae_p[i][r];
            a += __shfl_xor(a, 1); a += __shfl_xor(a, 2); a += __shfl_xor(a, 4); a += __shfl_xor(a, 8);
            if (rl == 0) rs_ae[(wm * 2 + i) * 16 + g * 4 + r][wn] = a;
        }
    __syncthreads();

    unsigned short* ho = heT + (size_t)bh * 32768;
    #pragma unroll
    for (int rep = 0; rep < 4; ++rep) {
        int id = rep * 1024 + tid;
        int f = id >> 5, pj = id & 31;
        int byte = (f * 512 + pj * 16) ^ ((f & 7) << 4);
        short8 v = *(const short8*)(tb2 + byte);
        *(short8*)(ho + (size_t)f * 256 + pj * 8) = v;
    }
    if (tid < 256) {
        float ae = rs_ae[tid][0] + rs_ae[tid][1];
        ev[((size_t)(n * 256 + tid)) * 8 + h] = expf(ae);
    }
}

// ---------------- k4_dense: rdm[n][l][p] = bit ? 1/den : 0  (bf16, h-shared)
__global__ __launch_bounds__(256) void k4_dense(const float* __restrict__ eu,
                                                const float* __restrict__ ev,
                                                const unsigned* __restrict__ bits,
                                                unsigned short* __restrict__ rdm) {
    __shared__ float ev_t[256][8];
    int b = blockIdx.x;
    int n = b >> 3, l0 = (b & 7) * 64;
    int tid = threadIdx.x;
    {
        const f32x4* src = (const f32x4*)(ev + (size_t)n * 2048);
        f32x4* dst = (f32x4*)&ev_t[0][0];
        dst[tid] = src[tid];
        dst[tid + 256] = src[tid + 256];
    }
    __syncthreads();
    int l = l0 + (tid >> 2), pq = tid & 3;
    size_t rowg = (size_t)n * 512 + l;
    f32x4 ea = *(const f32x4*)(eu + rowg * 8);
    f32x4 eb = *(const f32x4*)(eu + rowg * 8 + 4);
    unsigned w0 = bits[rowg * 8 + pq * 2], w1 = bits[rowg * 8 + pq * 2 + 1];
    for (int c = 0; c < 8; ++c) {
        short8 o8;
        #pragma unroll
        for (int k = 0; k < 8; ++k) {
            int pl = c * 8 + k;
            int p = pq * 64 + pl;
            f32x4 va = *(const f32x4*)&ev_t[p][0];
            f32x4 vb = *(const f32x4*)&ev_t[p][4];
            float den = ea.x * va.x + ea.y * va.y + ea.z * va.z + ea.w * va.w
                      + eb.x * vb.x + eb.y * vb.y + eb.z * vb.z + eb.w * vb.w;
            unsigned bit = (pl < 32) ? ((w0 >> pl) & 1u) : ((w1 >> (pl - 32)) & 1u);
            float r = bit ? rcp_f(den) : 0.0f;
            o8[k] = (short)bf16_rne(r);
        }
        *(short8*)(rdm + rowg * 256 + pq * 64 + c * 8) = o8;
    }
}

// ---------------- k5_mfma: x_nodes = 0.125*colsum(he) + A @ he; 1024 threads (16 waves)
__global__ __launch_bounds__(1024) void k5_mfma(const unsigned short* __restrict__ heT,
                                                const unsigned short* __restrict__ rdm,
                                                const float* __restrict__ eu,
                                                const float* __restrict__ ev,
                                                const unsigned* __restrict__ flags,
                                                const float* __restrict__ x,
                                                float* __restrict__ out) {
    __shared__ __align__(16) unsigned short heT_s[128 * 256];  // swizzled [e][p], 64 KB
    __shared__ __align__(16) unsigned short A_s[64 * 256];     // swizzled [l_loc][p], 32 KB
    __shared__ float evh_s[256];
    __shared__ float euh_s[64];
    __shared__ float cs_s[128];
    __shared__ float csr_s[4][128];
    __shared__ unsigned flg_s[64];

    int bid = blockIdx.x;
    int xcd = bid & 7, slot = bid >> 3;
    int n = xcd * 4 + (slot & 3), h = slot >> 2;
    int bh = n * 8 + h;
    int tid = threadIdx.x, lane = tid & 63, w = tid >> 6;

    const unsigned short* hb = heT + (size_t)bh * 32768;
    #pragma unroll
    for (int i = 0; i < 4; ++i) {
        int id = tid + i * 1024;
        int e = id >> 5, jj = id & 31;
        short8 v = *(const short8*)(hb + e * 256 + jj * 8);
        *(short8*)((char*)heT_s + ((e * 512 + jj * 16) ^ ((e & 7) << 4))) = v;
    }
    if (tid < 256) evh_s[tid] = ev[((size_t)(n * 256 + tid)) * 8 + h];
    __syncthreads();
    if (tid < 512) {
        int e = tid & 127, q = tid >> 7;
        float a = 0.f;
        #pragma unroll
        for (int j = 0; j < 8; ++j) {
            int byte = (e * 512 + (q * 64 + j * 8) * 2) ^ ((e & 7) << 4);
            short8 v = *(const short8*)((char*)heT_s + byte);
            #pragma unroll
            for (int k = 0; k < 8; ++k) a += bf2f(v[k]);
        }
        csr_s[q][e] = a;
    }
    __syncthreads();
    if (tid < 128) cs_s[tid] = 0.125f * (csr_s[0][tid] + csr_s[1][tid] + csr_s[2][tid] + csr_s[3][tid]);

    int rl = lane & 15, g = lane >> 4;
    int wm = w & 3, wn = w >> 2;
    int swz = (rl & 7) << 4;

    for (int lt = 0; lt < 8; ++lt) {
        int l0 = lt * 64;
        if (tid < 64) {
            euh_s[tid] = eu[((size_t)(n * 512 + l0 + tid)) * 8 + h];
            flg_s[tid] = flags[n * 512 + l0 + tid];
        }
        __syncthreads();
        {
            int l_loc = tid >> 4, p8 = (tid & 15) * 16;
            float euh = euh_s[l_loc];
            const unsigned short* rp = rdm + ((size_t)(n * 512 + l0 + l_loc)) * 256 + p8;
            #pragma unroll
            for (int c = 0; c < 2; ++c) {
                short8 rv = *(const short8*)(rp + c * 8);
                short8 o8;
                #pragma unroll
                for (int k = 0; k < 8; ++k) {
                    unsigned u = (unsigned)(unsigned short)rv[k];
                    float rf = __uint_as_float(u << 16);
                    float m125 = (u != 0u) ? -0.125f : 0.0f;
                    float a = fmaf(euh * evh_s[p8 + c * 8 + k], rf, m125);
                    o8[k] = (short)bf16_rne(a);
                }
                *(short8*)((char*)A_s + ((l_loc * 512 + (p8 + c * 8) * 2) ^ ((l_loc & 7) << 4))) = o8;
            }
        }
        __syncthreads();
        f32x4 acc[2];
        acc[0] = (f32x4){0.f, 0.f, 0.f, 0.f};
        acc[1] = (f32x4){0.f, 0.f, 0.f, 0.f};
        #pragma unroll
        for (int kt = 0; kt < 8; ++kt) {
            int arow = wm * 16 + rl;
            short8 af = *(const short8*)((char*)A_s + ((arow * 512 + kt * 64 + g * 16) ^ swz));
            short8 b0, b1;
            {
                int e0 = wn * 32 + rl;
                int e1 = wn * 32 + 16 + rl;
                b0 = *(const short8*)((char*)heT_s + ((e0 * 512 + kt * 64 + g * 16) ^ swz));
                b1 = *(const short8*)((char*)heT_s + ((e1 * 512 + kt * 64 + g * 16) ^ swz));
            }
            acc[0] = __builtin_amdgcn_mfma_f32_16x16x32_bf16(af, b0, acc[0], 0, 0, 0);
            acc[1] = __builtin_amdgcn_mfma_f32_16x16x32_bf16(af, b1, acc[1], 0, 0, 0);
        }
        #pragma unroll
        for (int j = 0; j < 2; ++j) {
            int e = wn * 32 + j * 16 + rl;
            float csv = cs_s[e];
            #pragma unroll
            for (int r = 0; r < 4; ++r) {
                int row = wm * 16 + g * 4 + r;
                int l = l0 + row;
                size_t addr = ((size_t)(n * 512 + l)) * 1024 + h * 128 + e;
                if (flg_s[row]) {
                    out[addr] = x[addr];
                } else {
                    out[addr] = gelu_f(acc[j][r] + csv);
                }
            }
        }
        __syncthreads();
    }
}

extern "C" void kernel_launch(void* const* d_in, const int* in_sizes, int n_in,
                              void* d_out, int out_size, void* d_ws, size_t ws_size,
                              hipStream_t stream) {
    (void)in_sizes; (void)n_in; (void)out_size; (void)ws_size;
    const float* x   = (const float*)d_in[0];
    const float* adj = (const float*)d_in[1];
    const float* W1  = (const float*)d_in[2];
    const float* b1  = (const float*)d_in[3];
    const float* W2  = (const float*)d_in[4];
    const float* W3  = (const float*)d_in[6];
    const float* b3  = (const float*)d_in[7];
    const float* W4  = (const float*)d_in[8];
    float* out = (float*)d_out;

    char* ws = (char*)d_ws;
    size_t off = 0;
    auto alloc = [&](size_t bytes) -> void* {
        void* p = ws + off;
        off += (bytes + 255) & ~(size_t)255;
        return p;
    };
    unsigned short* xhb = (unsigned short*)alloc((size_t)NB * HH * 65536 * 2);   // 33.5 MB bf16 k-packed
    unsigned short* sb  = (unsigned short*)alloc((size_t)NB * HH * LL * 2);      // bf16 s
    float* eu   = (float*)alloc((size_t)NB * LL * HH * 4);
    float* ev   = (float*)alloc((size_t)NB * PP * HH * 4);
    unsigned short* heT = (unsigned short*)alloc((size_t)NB * HH * EE * PP * 2); // 16.8 MB [(n,h)][f][p]
    unsigned short* rdm = (unsigned short*)alloc((size_t)NB * LL * PP * 2);      // 8.4 MB [n][l][p]
    unsigned* bits  = (unsigned*)alloc((size_t)NB * LL * 8 * 4);
    unsigned* bitsT = (unsigned*)alloc((size_t)NB * PP * 16 * 4);
    unsigned* flags = (unsigned*)alloc((size_t)NB * LL * 4);
    unsigned short* W1h = (unsigned short*)alloc(16384 * 2);
    unsigned short* W1l = (unsigned short*)alloc(16384 * 2);
    unsigned short* W3h = (unsigned short*)alloc(16384 * 2);
    unsigned short* W3l = (unsigned short*)alloc(16384 * 2);

    hipLaunchKernelGGL(kpack, dim3(2), dim3(256), 0, stream, W1, W3, W1h, W1l, W3h, W3l);
    hipLaunchKernelGGL(k0_bits, dim3(NB * 8), dim3(256), 0, stream, adj, bits, bitsT, flags);
    hipLaunchKernelGGL(gemm1c, dim3(1024), dim3(1024), 0, stream, x, W1h, W1l, b1, W2, W4, xhb, sb, eu);
    hipLaunchKernelGGL(k23_fused, dim3(NB * HH), dim3(1024), 0, stream, xhb, sb, bitsT, W3h, W3l, b3, W4, heT, ev);
    hipLaunchKernelGGL(k4_dense, dim3(NB * 8), dim3(256), 0, stream, eu, ev, bits, rdm);
    hipLaunchKernelGGL(k5_mfma, dim3(NB * HH), dim3(1024), 0, stream, heT, rdm, eu, ev, flags, x, out);
}

// Round 15
// 153.072 us; speedup vs baseline: 1.7831x; 1.1409x over previous
//
#include <hip/hip_runtime.h>
#include <math.h>

#define NB 32
#define LL 512
#define PP 256
#define HH 8
#define EE 128
#define DD 1024

typedef __attribute__((ext_vector_type(4))) float f32x4;
typedef __attribute__((ext_vector_type(8))) short short8;

__device__ __forceinline__ float rcp_f(float v) {
    float r; asm("v_rcp_f32 %0, %1" : "=v"(r) : "v"(v)); return r;
}
// tanh-form GELU (max |diff| vs erf-gelu ~3e-3), overflow-safe: v * sigmoid(2*0.7978846*(v+0.044715 v^3))
__device__ __forceinline__ float gelu_f(float v) {
    float z = v * (1.5957691216f + 0.0713548163f * v * v);
    float e = __expf(-z);
    return v * rcp_f(1.0f + e);
}
__device__ __forceinline__ unsigned short bf16_rne(float v) {
    unsigned u = __float_as_uint(v);
    unsigned r = u + 0x7FFFu + ((u >> 16) & 1u);
    return (unsigned short)(r >> 16);
}
__device__ __forceinline__ float bf2f(short s) {
    return __uint_as_float(((unsigned)(unsigned short)s) << 16);
}

// ---------------- kpack: W (128x128 fp32) -> bf16 hi/lo in MFMA B-fragment order
__global__ __launch_bounds__(256) void kpack(const float* __restrict__ W1,
                                             const float* __restrict__ W3,
                                             unsigned short* __restrict__ W1h,
                                             unsigned short* __restrict__ W1l,
                                             unsigned short* __restrict__ W3h,
                                             unsigned short* __restrict__ W3l) {
    const float* W = blockIdx.x ? W3 : W1;
    unsigned short* Ph = blockIdx.x ? W3h : W1h;
    unsigned short* Pl = blockIdx.x ? W3l : W1l;
    for (int i = threadIdx.x; i < 16384; i += 256) {
        int oct = i >> 10, col = (i >> 3) & 127, j = i & 7;
        float v = W[(oct * 8 + j) * 128 + col];
        unsigned short hb = bf16_rne(v);
        float hf = __uint_as_float((unsigned)hb << 16);
        Ph[i] = hb;
        Pl[i] = bf16_rne(v - hf);
    }
}

// ---------------- K0: pack mask to bits (row-major + col-major) + no-edge flags
__global__ __launch_bounds__(256) void k0_bits(const float* __restrict__ adj,
                                               unsigned* __restrict__ bits,
                                               unsigned* __restrict__ bitsT,
                                               unsigned* __restrict__ flags) {
    __shared__ unsigned lbits[64][8];
    int n  = blockIdx.x >> 3;
    int l0 = (blockIdx.x & 7) * 64;
    int lane = threadIdx.x & 63;
    int wv   = threadIdx.x >> 6;
    for (int r = wv; r < 64; r += 4) {
        int l = l0 + r;
        const float* row = adj + ((size_t)n * LL + l) * PP;
        int cnt = 0;
        for (int c = 0; c < 4; ++c) {
            float v = row[c * 64 + lane];
            unsigned long long b = __ballot(v != 0.0f);
            if (lane == 0) {
                lbits[r][c * 2]     = (unsigned)b;
                lbits[r][c * 2 + 1] = (unsigned)(b >> 32);
                cnt += __popcll(b);
            }
        }
        if (lane == 0) {
            flags[n * LL + l] = (cnt == 0) ? 1u : 0u;
            for (int w = 0; w < 8; ++w)
                bits[((size_t)n * LL + l) * 8 + w] = lbits[r][w];
        }
    }
    __syncthreads();
    int p = threadIdx.x;
    unsigned w0 = 0, w1 = 0;
    int wp = p >> 5, bp = p & 31;
    for (int j = 0; j < 32; ++j) {
        w0 |= ((lbits[j][wp] >> bp) & 1u) << j;
        w1 |= ((lbits[j + 32][wp] >> bp) & 1u) << j;
    }
    bitsT[((size_t)n * PP + p) * 16 + (l0 >> 5)]     = w0;
    bitsT[((size_t)n * PP + p) * 16 + (l0 >> 5) + 1] = w1;
}

// ---------------- gemm1c: xh = x@W1+b1; single-pass bf16 MFMA (precision lost at bf16 storage anyway)
__global__ __launch_bounds__(1024) void gemm1c(const float* __restrict__ A,
                                               const unsigned short* __restrict__ Bhi,
                                               const float* __restrict__ bias,
                                               const float* __restrict__ W2,
                                               const float* __restrict__ W4,
                                               unsigned short* __restrict__ xhb,
                                               unsigned short* __restrict__ sb,
                                               float* __restrict__ eu) {
    __shared__ __align__(16) char buf[32768];   // As half (32 KB) then tbuf (32 KB)
    __shared__ float rs4[4][128][2];
    __shared__ float rs[128][2];
    float* As = (float*)buf;
    unsigned short* tbuf = (unsigned short*)buf;
    int tid = threadIdx.x, lane = tid & 63, w = tid >> 6;
    int b = blockIdx.x;
    size_t blockRow0 = (size_t)b * 128;
    int rl = lane & 15, g = lane >> 4;
    int mt = w & 7, eh = w >> 3;

    f32x4 acc[4];
    #pragma unroll
    for (int nt = 0; nt < 4; ++nt) acc[nt] = (f32x4){0.f, 0.f, 0.f, 0.f};

    #pragma unroll
    for (int kh = 0; kh < 2; ++kh) {
        if (kh) __syncthreads();
        {   // stage 128 rows x 64 cols fp32, coalesced, row-swizzled
            const float* Ag = A + blockRow0 * 128 + kh * 64;
            #pragma unroll
            for (int i = 0; i < 2; ++i) {
                int idx = i * 1024 + tid;
                int row = idx >> 4, c4 = idx & 15;
                f32x4 v = *(const f32x4*)(Ag + (size_t)row * 128 + c4 * 4);
                *(f32x4*)((char*)As + ((row * 256 + c4 * 16) ^ ((row & 7) << 5))) = v;
            }
        }
        __syncthreads();
        #pragma unroll
        for (int kcl = 0; kcl < 2; ++kcl) {
            int kc = kh * 2 + kcl;
            short8 ah;
            {
                int arow = mt * 16 + rl;
                int cb = (kcl * 32 + g * 8) * 4;
                int sw = (arow & 7) << 5;
                f32x4 a0 = *(const f32x4*)((char*)As + ((arow * 256 + cb) ^ sw));
                f32x4 a1 = *(const f32x4*)((char*)As + ((arow * 256 + cb + 16) ^ sw));
                ah[0] = (short)bf16_rne(a0.x); ah[1] = (short)bf16_rne(a0.y);
                ah[2] = (short)bf16_rne(a0.z); ah[3] = (short)bf16_rne(a0.w);
                ah[4] = (short)bf16_rne(a1.x); ah[5] = (short)bf16_rne(a1.y);
                ah[6] = (short)bf16_rne(a1.z); ah[7] = (short)bf16_rne(a1.w);
            }
            #pragma unroll
            for (int ntl = 0; ntl < 4; ++ntl) {
                int oct = kc * 4 + g, col = eh * 64 + ntl * 16 + rl;
                short8 bh = *(const short8*)(Bhi + ((size_t)(oct * 128 + col)) * 8);
                acc[ntl] = __builtin_amdgcn_mfma_f32_16x16x32_bf16(ah, bh, acc[ntl], 0, 0, 0);
            }
        }
    }
    __syncthreads();   // As dead; buf becomes tbuf

    // Phase B: acc -> tbuf[l_loc][e][h], ushort4 (4 consecutive h), conflict-free
    {
        int l_loc = mt * 2 + (g >> 1);
        int hbase2 = (g & 1) * 8;
        #pragma unroll
        for (int ntl = 0; ntl < 4; ++ntl) {
            int col = eh * 64 + ntl * 16 + rl;
            float bv = bias[col];
            ushort4 o;
            o.x = bf16_rne(acc[ntl][0] + bv);
            o.y = bf16_rne(acc[ntl][1] + bv);
            o.z = bf16_rne(acc[ntl][2] + bv);
            o.w = bf16_rne(acc[ntl][3] + bv);
            *(ushort4*)((char*)tbuf + (l_loc * 2048 + col * 16 + hbase2)) = o;
        }
    }
    __syncthreads();

    // Phase C: per-row gelu sums; thread = (eq, l_loc, ec)
    {
        int ec = tid & 15, l_loc = (tid >> 4) & 15, eq = tid >> 8;
        float xv_p[8] = {0,0,0,0,0,0,0,0};
        float an_p[8] = {0,0,0,0,0,0,0,0};
        #pragma unroll
        for (int i = 0; i < 2; ++i) {
            int e = (eq * 2 + i) * 16 + ec;
            short8 v = *(const short8*)((char*)tbuf + (l_loc * 2048 + e * 16));
            float w2 = W2[e], w4 = W4[128 + e];
            #pragma unroll
            for (int h = 0; h < 8; ++h) {
                float gv = gelu_f(bf2f(v[h]));
                xv_p[h] += gv * w2;
                an_p[h] += gv * w4;
            }
        }
        #pragma unroll
        for (int h = 0; h < 8; ++h) {
            #pragma unroll
            for (int m = 1; m < 16; m <<= 1) {
                xv_p[h] += __shfl_xor(xv_p[h], m);
                an_p[h] += __shfl_xor(an_p[h], m);
            }
        }
        if (ec == 0) {
            #pragma unroll
            for (int h = 0; h < 8; ++h) {
                rs4[eq][l_loc * 8 + h][0] = xv_p[h];
                rs4[eq][l_loc * 8 + h][1] = an_p[h];
            }
        }
    }

    // Phase D: tbuf -> xhb k-packed
    int n = b >> 5, kg0 = (b & 31) * 2;
    #pragma unroll
    for (int rep = 0; rep < 2; ++rep) {
        int id = rep * 1024 + tid;
        int h = (id >> 8) & 7, kg = (id >> 7) & 1, e = id & 127;
        short8 v;
        #pragma unroll
        for (int j = 0; j < 8; ++j)
            v[j] = (short)*(const unsigned short*)((char*)tbuf + ((kg * 8 + j) * 2048 + e * 16 + h * 2));
        *(short8*)(xhb + ((size_t)(n * 8 + h)) * 65536 + (size_t)((kg0 + kg) * 128 + e) * 8) = v;
    }
    __syncthreads();

    if (tid < 128) {
        rs[tid][0] = rs4[0][tid][0] + rs4[1][tid][0] + rs4[2][tid][0] + rs4[3][tid][0];
        rs[tid][1] = rs4[0][tid][1] + rs4[1][tid][1] + rs4[2][tid][1] + rs4[3][tid][1];
    }
    __syncthreads();
    if (tid < 16) {
        int l = (b & 31) * 16 + tid;
        float xv[8], an[8];
        #pragma unroll
        for (int h = 0; h < 8; ++h) { xv[h] = rs[tid * 8 + h][0]; an[h] = rs[tid * 8 + h][1]; }
        float mx = xv[0];
        #pragma unroll
        for (int h = 1; h < 8; ++h) mx = fmaxf(mx, xv[h]);
        float ex[8], ssum = 0.f;
        #pragma unroll
        for (int h = 0; h < 8; ++h) { ex[h] = expf(xv[h] - mx); ssum += ex[h]; }
        float inv = 1.0f / ssum;
        #pragma unroll
        for (int h = 0; h < 8; ++h)
            sb[((size_t)(n * 8 + h)) * 512 + l] = bf16_rne(ex[h] * inv);
        float mxa = an[0];
        #pragma unroll
        for (int h = 1; h < 8; ++h) mxa = fmaxf(mxa, an[h]);
        f32x4 e0, e1;
        #pragma unroll
        for (int h = 0; h < 4; ++h) e0[h] = expf(an[h] - mxa);
        #pragma unroll
        for (int h = 0; h < 4; ++h) e1[h] = expf(an[4 + h] - mxa);
        float* ep = eu + ((size_t)(n * 512 + l)) * 8;
        *(f32x4*)ep = e0;
        *(f32x4*)(ep + 4) = e1;
    }
}

// ---------------- k23_fused: stage1 heg = gelu(A'@xh) (LDS bf16) ; stage2 he = heg@W3+b3
__global__ __launch_bounds__(1024) void k23_fused(const unsigned short* __restrict__ xhb,
                                                  const unsigned short* __restrict__ s_in,
                                                  const unsigned* __restrict__ bitsT,
                                                  const unsigned short* __restrict__ W3h,
                                                  const float* __restrict__ b3,
                                                  const float* __restrict__ W4,
                                                  unsigned short* __restrict__ heT,
                                                  float* __restrict__ ev) {
    __shared__ __align__(16) unsigned short kpk[65536];    // 128 KB; after stage1: A2 (64KB) | tbuf (64KB)
    __shared__ unsigned bT_s[16 * 256];                    // 16 KB
    __shared__ __align__(16) unsigned short smb_s[512];    // 1 KB
    __shared__ float rs_ae[256][2];                        // 2 KB
    int bh = blockIdx.x;
    int n = bh >> 3, h = bh & 7;
    int tid = threadIdx.x, lane = tid & 63, w = tid >> 6;
    int rl = lane & 15, g = lane >> 4;

    {
        int p = tid >> 2, q = tid & 3;
        uint4 wds = *(const uint4*)(bitsT + ((size_t)(n * 256 + p)) * 16 + q * 4);
        bT_s[(q * 4 + 0) * 256 + p] = wds.x;
        bT_s[(q * 4 + 1) * 256 + p] = wds.y;
        bT_s[(q * 4 + 2) * 256 + p] = wds.z;
        bT_s[(q * 4 + 3) * 256 + p] = wds.w;
    }
    if (tid < 512) smb_s[tid] = s_in[(size_t)bh * 512 + tid];
    {
        const unsigned short* xb = xhb + (size_t)bh * 65536;
        #pragma unroll
        for (int rep = 0; rep < 8; ++rep) {
            int idx = rep * 1024 + tid;
            *(short8*)&kpk[idx * 8] = *(const short8*)(xb + (size_t)idx * 8);
        }
    }
    __syncthreads();

    // ---- stage 1: heg[p][e] = A' @ xh (acc in regs)
    int wm = w & 7, wn = w >> 3;
    f32x4 acc[2][4];
    #pragma unroll
    for (int i = 0; i < 2; ++i)
        #pragma unroll
        for (int nt = 0; nt < 4; ++nt) acc[i][nt] = (f32x4){0.f, 0.f, 0.f, 0.f};

    for (int kt = 0; kt < 16; ++kt) {
        short8 sv = *(const short8*)&smb_s[kt * 32 + g * 8];
        short8 bfr[4];
        #pragma unroll
        for (int nt = 0; nt < 4; ++nt)
            bfr[nt] = *(const short8*)&kpk[(((kt * 4 + g) << 7) + wn * 64 + nt * 16 + rl) * 8];
        #pragma unroll
        for (int i = 0; i < 2; ++i) {
            unsigned word = bT_s[kt * 256 + (wm * 2 + i) * 16 + rl];
            unsigned byte = (word >> (g * 8)) & 255u;
            short8 af;
            #pragma unroll
            for (int j = 0; j < 8; ++j)
                af[j] = ((byte >> j) & 1u) ? sv[j] : (short)0x3E00;
            #pragma unroll
            for (int nt = 0; nt < 4; ++nt)
                acc[i][nt] = __builtin_amdgcn_mfma_f32_16x16x32_bf16(af, bfr[nt], acc[i][nt], 0, 0, 0);
        }
    }
    __syncthreads();   // all waves done reading kpk; reuse as A2 | tbuf

    char* A2  = (char*)kpk;           // A2[p][e] bf16, row 256B, swz ^((p&15)<<4)
    char* tb2 = (char*)kpk + 65536;   // tbuf he[f][p] bf16, row 512B, swz ^((f&7)<<4)

    #pragma unroll
    for (int i = 0; i < 2; ++i)
        #pragma unroll
        for (int nt = 0; nt < 4; ++nt) {
            int e = wn * 64 + nt * 16 + rl;
            #pragma unroll
            for (int r = 0; r < 4; ++r) {
                int p = (wm * 2 + i) * 16 + g * 4 + r;
                *(unsigned short*)(A2 + ((p * 256 + e * 2) ^ ((p & 15) << 4))) =
                    bf16_rne(gelu_f(acc[i][nt][r]));
            }
        }
    __syncthreads();

    // ---- stage 2: he[p][f] = A2 @ W3h + b3 (single-pass; A2 already bf16)
    f32x4 acc2[2][4];
    #pragma unroll
    for (int i = 0; i < 2; ++i)
        #pragma unroll
        for (int nt = 0; nt < 4; ++nt) acc2[i][nt] = (f32x4){0.f, 0.f, 0.f, 0.f};

    #pragma unroll
    for (int kt2 = 0; kt2 < 4; ++kt2) {
        short8 af2[2];
        #pragma unroll
        for (int i = 0; i < 2; ++i) {
            int p = (wm * 2 + i) * 16 + rl;
            af2[i] = *(const short8*)(A2 + ((p * 256 + (kt2 * 32 + g * 8) * 2) ^ ((p & 15) << 4)));
        }
        #pragma unroll
        for (int nt = 0; nt < 4; ++nt) {
            int oct = kt2 * 4 + g, col = (wn * 4 + nt) * 16 + rl;
            short8 bhv = *(const short8*)(W3h + ((size_t)(oct * 128 + col)) * 8);
            #pragma unroll
            for (int i = 0; i < 2; ++i)
                acc2[i][nt] = __builtin_amdgcn_mfma_f32_16x16x32_bf16(af2[i], bhv, acc2[i][nt], 0, 0, 0);
        }
    }

    // ---- epilogue: bias, ae partials, he -> tbuf (transposed)
    float ae_p[2][4] = {{0.f,0.f,0.f,0.f},{0.f,0.f,0.f,0.f}};
    #pragma unroll
    for (int nt = 0; nt < 4; ++nt) {
        int f = (wn * 4 + nt) * 16 + rl;
        float bv = b3[f], w4v = W4[f];
        #pragma unroll
        for (int i = 0; i < 2; ++i) {
            float v0 = acc2[i][nt][0] + bv;
            float v1 = acc2[i][nt][1] + bv;
            float v2 = acc2[i][nt][2] + bv;
            float v3 = acc2[i][nt][3] + bv;
            ae_p[i][0] += gelu_f(v0) * w4v;
            ae_p[i][1] += gelu_f(v1) * w4v;
            ae_p[i][2] += gelu_f(v2) * w4v;
            ae_p[i][3] += gelu_f(v3) * w4v;
            int p0 = (wm * 2 + i) * 16 + g * 4;
            int byte = (f * 512 + p0 * 2) ^ ((f & 7) << 4);
            *(ushort4*)(tb2 + byte) =
                make_ushort4(bf16_rne(v0), bf16_rne(v1), bf16_rne(v2), bf16_rne(v3));
        }
    }
    #pragma unroll
    for (int i = 0; i < 2; ++i)
        #pragma unroll
        for (int r = 0; r < 4; ++r) {
            float a = ae_p[i][r];
            a += __shfl_xor(a, 1); a += __shfl_xor(a, 2); a += __shfl_xor(a, 4); a += __shfl_xor(a, 8);
            if (rl == 0) rs_ae[(wm * 2 + i) * 16 + g * 4 + r][wn] = a;
        }
    __syncthreads();

    unsigned short* ho = heT + (size_t)bh * 32768;
    #pragma unroll
    for (int rep = 0; rep < 4; ++rep) {
        int id = rep * 1024 + tid;
        int f = id >> 5, pj = id & 31;
        int byte = (f * 512 + pj * 16) ^ ((f & 7) << 4);
        short8 v = *(const short8*)(tb2 + byte);
        *(short8*)(ho + (size_t)f * 256 + pj * 8) = v;
    }
    if (tid < 256) {
        float ae = rs_ae[tid][0] + rs_ae[tid][1];
        ev[((size_t)(n * 256 + tid)) * 8 + h] = expf(ae);
    }
}

// ---------------- k4_dense: rdm[n][l][p] = bit ? 1/den : 0  (bf16, h-shared)
__global__ __launch_bounds__(256) void k4_dense(const float* __restrict__ eu,
                                                const float* __restrict__ ev,
                                                const unsigned* __restrict__ bits,
                                                unsigned short* __restrict__ rdm) {
    __shared__ float ev_t[256][8];
    int b = blockIdx.x;
    int n = b >> 3, l0 = (b & 7) * 64;
    int tid = threadIdx.x;
    {
        const f32x4* src = (const f32x4*)(ev + (size_t)n * 2048);
        f32x4* dst = (f32x4*)&ev_t[0][0];
        dst[tid] = src[tid];
        dst[tid + 256] = src[tid + 256];
    }
    __syncthreads();
    int l = l0 + (tid >> 2), pq = tid & 3;
    size_t rowg = (size_t)n * 512 + l;
    f32x4 ea = *(const f32x4*)(eu + rowg * 8);
    f32x4 eb = *(const f32x4*)(eu + rowg * 8 + 4);
    unsigned w0 = bits[rowg * 8 + pq * 2], w1 = bits[rowg * 8 + pq * 2 + 1];
    for (int c = 0; c < 8; ++c) {
        short8 o8;
        #pragma unroll
        for (int k = 0; k < 8; ++k) {
            int pl = c * 8 + k;
            int p = pq * 64 + pl;
            f32x4 va = *(const f32x4*)&ev_t[p][0];
            f32x4 vb = *(const f32x4*)&ev_t[p][4];
            float den = ea.x * va.x + ea.y * va.y + ea.z * va.z + ea.w * va.w
                      + eb.x * vb.x + eb.y * vb.y + eb.z * vb.z + eb.w * vb.w;
            unsigned bit = (pl < 32) ? ((w0 >> pl) & 1u) : ((w1 >> (pl - 32)) & 1u);
            float r = bit ? rcp_f(den) : 0.0f;
            o8[k] = (short)bf16_rne(r);
        }
        *(short8*)(rdm + rowg * 256 + pq * 64 + c * 8) = o8;
    }
}

// ---------------- k5_mfma: x_nodes = 0.125*colsum(he) + A @ he; 1024 threads (16 waves)
__global__ __launch_bounds__(1024) void k5_mfma(const unsigned short* __restrict__ heT,
                                                const unsigned short* __restrict__ rdm,
                                                const float* __restrict__ eu,
                                                const float* __restrict__ ev,
                                                const unsigned* __restrict__ flags,
                                                const float* __restrict__ x,
                                                float* __restrict__ out) {
    __shared__ __align__(16) unsigned short heT_s[128 * 256];  // swizzled [e][p], 64 KB
    __shared__ __align__(16) unsigned short A_s[64 * 256];     // swizzled [l_loc][p], 32 KB
    __shared__ float evh_s[256];
    __shared__ float euh_s[64];
    __shared__ float cs_s[128];
    __shared__ float csr_s[4][128];
    __shared__ unsigned flg_s[64];

    int bid = blockIdx.x;
    int xcd = bid & 7, slot = bid >> 3;
    int n = xcd * 4 + (slot & 3), h = slot >> 2;
    int bh = n * 8 + h;
    int tid = threadIdx.x, lane = tid & 63, w = tid >> 6;

    const unsigned short* hb = heT + (size_t)bh * 32768;
    #pragma unroll
    for (int i = 0; i < 4; ++i) {
        int id = tid + i * 1024;
        int e = id >> 5, jj = id & 31;
        short8 v = *(const short8*)(hb + e * 256 + jj * 8);
        *(short8*)((char*)heT_s + ((e * 512 + jj * 16) ^ ((e & 7) << 4))) = v;
    }
    if (tid < 256) evh_s[tid] = ev[((size_t)(n * 256 + tid)) * 8 + h];
    __syncthreads();
    if (tid < 512) {
        int e = tid & 127, q = tid >> 7;
        float a = 0.f;
        #pragma unroll
        for (int j = 0; j < 8; ++j) {
            int byte = (e * 512 + (q * 64 + j * 8) * 2) ^ ((e & 7) << 4);
            short8 v = *(const short8*)((char*)heT_s + byte);
            #pragma unroll
            for (int k = 0; k < 8; ++k) a += bf2f(v[k]);
        }
        csr_s[q][e] = a;
    }
    __syncthreads();
    if (tid < 128) cs_s[tid] = 0.125f * (csr_s[0][tid] + csr_s[1][tid] + csr_s[2][tid] + csr_s[3][tid]);

    int rl = lane & 15, g = lane >> 4;
    int wm = w & 3, wn = w >> 2;
    int swz = (rl & 7) << 4;

    for (int lt = 0; lt < 8; ++lt) {
        int l0 = lt * 64;
        if (tid < 64) {
            euh_s[tid] = eu[((size_t)(n * 512 + l0 + tid)) * 8 + h];
            flg_s[tid] = flags[n * 512 + l0 + tid];
        }
        __syncthreads();
        {
            int l_loc = tid >> 4, p8 = (tid & 15) * 16;
            float euh = euh_s[l_loc];
            const unsigned short* rp = rdm + ((size_t)(n * 512 + l0 + l_loc)) * 256 + p8;
            #pragma unroll
            for (int c = 0; c < 2; ++c) {
                short8 rv = *(const short8*)(rp + c * 8);
                short8 o8;
                #pragma unroll
                for (int k = 0; k < 8; ++k) {
                    unsigned u = (unsigned)(unsigned short)rv[k];
                    float rf = __uint_as_float(u << 16);
                    float m125 = (u != 0u) ? -0.125f : 0.0f;
                    float a = fmaf(euh * evh_s[p8 + c * 8 + k], rf, m125);
                    o8[k] = (short)bf16_rne(a);
                }
                *(short8*)((char*)A_s + ((l_loc * 512 + (p8 + c * 8) * 2) ^ ((l_loc & 7) << 4))) = o8;
            }
        }
        __syncthreads();
        f32x4 acc[2];
        acc[0] = (f32x4){0.f, 0.f, 0.f, 0.f};
        acc[1] = (f32x4){0.f, 0.f, 0.f, 0.f};
        #pragma unroll
        for (int kt = 0; kt < 8; ++kt) {
            int arow = wm * 16 + rl;
            short8 af = *(const short8*)((char*)A_s + ((arow * 512 + kt * 64 + g * 16) ^ swz));
            short8 b0, b1;
            {
                int e0 = wn * 32 + rl;
                int e1 = wn * 32 + 16 + rl;
                b0 = *(const short8*)((char*)heT_s + ((e0 * 512 + kt * 64 + g * 16) ^ swz));
                b1 = *(const short8*)((char*)heT_s + ((e1 * 512 + kt * 64 + g * 16) ^ swz));
            }
            acc[0] = __builtin_amdgcn_mfma_f32_16x16x32_bf16(af, b0, acc[0], 0, 0, 0);
            acc[1] = __builtin_amdgcn_mfma_f32_16x16x32_bf16(af, b1, acc[1], 0, 0, 0);
        }
        #pragma unroll
        for (int j = 0; j < 2; ++j) {
            int e = wn * 32 + j * 16 + rl;
            float csv = cs_s[e];
            #pragma unroll
            for (int r = 0; r < 4; ++r) {
                int row = wm * 16 + g * 4 + r;
                int l = l0 + row;
                size_t addr = ((size_t)(n * 512 + l)) * 1024 + h * 128 + e;
                if (flg_s[row]) {
                    out[addr] = x[addr];
                } else {
                    out[addr] = gelu_f(acc[j][r] + csv);
                }
            }
        }
        __syncthreads();
    }
}

extern "C" void kernel_launch(void* const* d_in, const int* in_sizes, int n_in,
                              void* d_out, int out_size, void* d_ws, size_t ws_size,
                              hipStream_t stream) {
    (void)in_sizes; (void)n_in; (void)out_size; (void)ws_size;
    const float* x   = (const float*)d_in[0];
    const float* adj = (const float*)d_in[1];
    const float* W1  = (const float*)d_in[2];
    const float* b1  = (const float*)d_in[3];
    const float* W2  = (const float*)d_in[4];
    const float* W3  = (const float*)d_in[6];
    const float* b3  = (const float*)d_in[7];
    const float* W4  = (const float*)d_in[8];
    float* out = (float*)d_out;

    char* ws = (char*)d_ws;
    size_t off = 0;
    auto alloc = [&](size_t bytes) -> void* {
        void* p = ws + off;
        off += (bytes + 255) & ~(size_t)255;
        return p;
    };
    unsigned short* xhb = (unsigned short*)alloc((size_t)NB * HH * 65536 * 2);   // 33.5 MB bf16 k-packed
    unsigned short* sb  = (unsigned short*)alloc((size_t)NB * HH * LL * 2);      // bf16 s
    float* eu   = (float*)alloc((size_t)NB * LL * HH * 4);
    float* ev   = (float*)alloc((size_t)NB * PP * HH * 4);
    unsigned short* heT = (unsigned short*)alloc((size_t)NB * HH * EE * PP * 2); // 16.8 MB [(n,h)][f][p]
    unsigned short* rdm = (unsigned short*)alloc((size_t)NB * LL * PP * 2);      // 8.4 MB [n][l][p]
    unsigned* bits  = (unsigned*)alloc((size_t)NB * LL * 8 * 4);
    unsigned* bitsT = (unsigned*)alloc((size_t)NB * PP * 16 * 4);
    unsigned* flags = (unsigned*)alloc((size_t)NB * LL * 4);
    unsigned short* W1h = (unsigned short*)alloc(16384 * 2);
    unsigned short* W1l = (unsigned short*)alloc(16384 * 2);
    unsigned short* W3h = (unsigned short*)alloc(16384 * 2);
    unsigned short* W3l = (unsigned short*)alloc(16384 * 2);

    hipLaunchKernelGGL(kpack, dim3(2), dim3(256), 0, stream, W1, W3, W1h, W1l, W3h, W3l);
    hipLaunchKernelGGL(k0_bits, dim3(NB * 8), dim3(256), 0, stream, adj, bits, bitsT, flags);
    hipLaunchKernelGGL(gemm1c, dim3(1024), dim3(1024), 0, stream, x, W1h, b1, W2, W4, xhb, sb, eu);
    hipLaunchKernelGGL(k23_fused, dim3(NB * HH), dim3(1024), 0, stream, xhb, sb, bitsT, W3h, b3, W4, heT, ev);
    hipLaunchKernelGGL(k4_dense, dim3(NB * 8), dim3(256), 0, stream, eu, ev, bits, rdm);
    hipLaunchKernelGGL(k5_mfma, dim3(NB * HH), dim3(1024), 0, stream, heT, rdm, eu, ev, flags, x, out);
}

// Round 16
// 142.109 us; speedup vs baseline: 1.9206x; 1.0771x over previous
//
#include <hip/hip_runtime.h>
#include <math.h>

#define NB 32
#define LL 512
#define PP 256
#define HH 8
#define EE 128
#define DD 1024

typedef __attribute__((ext_vector_type(4))) float f32x4;
typedef __attribute__((ext_vector_type(8))) short short8;

__device__ __forceinline__ float rcp_f(float v) {
    float r; asm("v_rcp_f32 %0, %1" : "=v"(r) : "v"(v)); return r;
}
// tanh-form GELU (max |diff| vs erf-gelu ~3e-3), overflow-safe
__device__ __forceinline__ float gelu_f(float v) {
    float z = v * (1.5957691216f + 0.0713548163f * v * v);
    float e = __expf(-z);
    return v * rcp_f(1.0f + e);
}
__device__ __forceinline__ unsigned short bf16_rne(float v) {
    unsigned u = __float_as_uint(v);
    unsigned r = u + 0x7FFFu + ((u >> 16) & 1u);
    return (unsigned short)(r >> 16);
}
__device__ __forceinline__ float bf2f(short s) {
    return __uint_as_float(((unsigned)(unsigned short)s) << 16);
}

// ---------------- kpack: W (128x128 fp32) -> bf16 hi/lo in MFMA B-fragment order
__global__ __launch_bounds__(256) void kpack(const float* __restrict__ W1,
                                             const float* __restrict__ W3,
                                             unsigned short* __restrict__ W1h,
                                             unsigned short* __restrict__ W1l,
                                             unsigned short* __restrict__ W3h,
                                             unsigned short* __restrict__ W3l) {
    const float* W = blockIdx.x ? W3 : W1;
    unsigned short* Ph = blockIdx.x ? W3h : W1h;
    unsigned short* Pl = blockIdx.x ? W3l : W1l;
    for (int i = threadIdx.x; i < 16384; i += 256) {
        int oct = i >> 10, col = (i >> 3) & 127, j = i & 7;
        float v = W[(oct * 8 + j) * 128 + col];
        unsigned short hb = bf16_rne(v);
        float hf = __uint_as_float((unsigned)hb << 16);
        Ph[i] = hb;
        Pl[i] = bf16_rne(v - hf);
    }
}

// ---------------- K0: pack mask to bits (row-major + col-major) + no-edge flags
__global__ __launch_bounds__(256) void k0_bits(const float* __restrict__ adj,
                                               unsigned* __restrict__ bits,
                                               unsigned* __restrict__ bitsT,
                                               unsigned* __restrict__ flags) {
    __shared__ unsigned lbits[64][8];
    int n  = blockIdx.x >> 3;
    int l0 = (blockIdx.x & 7) * 64;
    int lane = threadIdx.x & 63;
    int wv   = threadIdx.x >> 6;
    for (int r = wv; r < 64; r += 4) {
        int l = l0 + r;
        const float* row = adj + ((size_t)n * LL + l) * PP;
        int cnt = 0;
        for (int c = 0; c < 4; ++c) {
            float v = row[c * 64 + lane];
            unsigned long long b = __ballot(v != 0.0f);
            if (lane == 0) {
                lbits[r][c * 2]     = (unsigned)b;
                lbits[r][c * 2 + 1] = (unsigned)(b >> 32);
                cnt += __popcll(b);
            }
        }
        if (lane == 0) {
            flags[n * LL + l] = (cnt == 0) ? 1u : 0u;
            for (int w = 0; w < 8; ++w)
                bits[((size_t)n * LL + l) * 8 + w] = lbits[r][w];
        }
    }
    __syncthreads();
    int p = threadIdx.x;
    unsigned w0 = 0, w1 = 0;
    int wp = p >> 5, bp = p & 31;
    for (int j = 0; j < 32; ++j) {
        w0 |= ((lbits[j][wp] >> bp) & 1u) << j;
        w1 |= ((lbits[j + 32][wp] >> bp) & 1u) << j;
    }
    bitsT[((size_t)n * PP + p) * 16 + (l0 >> 5)]     = w0;
    bitsT[((size_t)n * PP + p) * 16 + (l0 >> 5) + 1] = w1;
}

// ---------------- gemm1c: xh = x@W1+b1; 512 thr / 8 waves / 64 rows; 4 blocks/CU
// Full-tile A stage (one barrier round); tbuf [l_loc(8)][e(128)][h(8)] bf16.
__global__ __launch_bounds__(512) void gemm1c(const float* __restrict__ A,
                                              const unsigned short* __restrict__ Bhi,
                                              const float* __restrict__ bias,
                                              const float* __restrict__ W2,
                                              const float* __restrict__ W4,
                                              unsigned short* __restrict__ xhb,
                                              unsigned short* __restrict__ sb,
                                              float* __restrict__ eu) {
    __shared__ __align__(16) char buf[32768];   // As full tile (32 KB) then tbuf (16 KB)
    __shared__ float rs4[4][64][2];
    __shared__ float rs[64][2];
    float* As = (float*)buf;
    unsigned short* tbuf = (unsigned short*)buf;
    int tid = threadIdx.x, lane = tid & 63, w = tid >> 6;
    int b = blockIdx.x;                 // 2048 blocks, 64 rows each
    size_t blockRow0 = (size_t)b * 64;
    int rl = lane & 15, g = lane >> 4;
    int mt = w & 3, eh = w >> 2;        // 4 m-tiles x 2 e-halves

    {   // stage full 64x128 fp32 tile, coalesced, row-swizzled
        const f32x4* Ag = (const f32x4*)(A + blockRow0 * 128);
        #pragma unroll
        for (int i = 0; i < 4; ++i) {
            int idx = i * 512 + tid;
            int row = idx >> 5, c4 = idx & 31;
            f32x4 v = Ag[idx];
            *(f32x4*)((char*)As + ((row * 512 + c4 * 16) ^ ((row & 7) << 5))) = v;
        }
    }
    __syncthreads();

    f32x4 acc[4];
    #pragma unroll
    for (int nt = 0; nt < 4; ++nt) acc[nt] = (f32x4){0.f, 0.f, 0.f, 0.f};

    #pragma unroll
    for (int kc = 0; kc < 4; ++kc) {
        short8 ah;
        {
            int arow = mt * 16 + rl;
            int cb = (kc * 32 + g * 8) * 4;
            int sw = (arow & 7) << 5;
            f32x4 a0 = *(const f32x4*)((char*)As + ((arow * 512 + cb) ^ sw));
            f32x4 a1 = *(const f32x4*)((char*)As + ((arow * 512 + cb + 16) ^ sw));
            ah[0] = (short)bf16_rne(a0.x); ah[1] = (short)bf16_rne(a0.y);
            ah[2] = (short)bf16_rne(a0.z); ah[3] = (short)bf16_rne(a0.w);
            ah[4] = (short)bf16_rne(a1.x); ah[5] = (short)bf16_rne(a1.y);
            ah[6] = (short)bf16_rne(a1.z); ah[7] = (short)bf16_rne(a1.w);
        }
        #pragma unroll
        for (int ntl = 0; ntl < 4; ++ntl) {
            int oct = kc * 4 + g, col = eh * 64 + ntl * 16 + rl;
            short8 bh = *(const short8*)(Bhi + ((size_t)(oct * 128 + col)) * 8);
            acc[ntl] = __builtin_amdgcn_mfma_f32_16x16x32_bf16(ah, bh, acc[ntl], 0, 0, 0);
        }
    }
    __syncthreads();   // As dead; buf becomes tbuf

    // Phase B: acc -> tbuf[l_loc][e][h], ushort4 (4 consecutive h), conflict-free
    {
        int l_loc = mt * 2 + (g >> 1);
        int hbase2 = (g & 1) * 8;
        #pragma unroll
        for (int ntl = 0; ntl < 4; ++ntl) {
            int col = eh * 64 + ntl * 16 + rl;
            float bv = bias[col];
            ushort4 o;
            o.x = bf16_rne(acc[ntl][0] + bv);
            o.y = bf16_rne(acc[ntl][1] + bv);
            o.z = bf16_rne(acc[ntl][2] + bv);
            o.w = bf16_rne(acc[ntl][3] + bv);
            *(ushort4*)((char*)tbuf + (l_loc * 2048 + col * 16 + hbase2)) = o;
        }
    }
    __syncthreads();

    // Phase C: per-row gelu sums; thread = (eq 0..3, l_loc 0..7, ec 0..15)
    {
        int ec = tid & 15, l_loc = (tid >> 4) & 7, eq = tid >> 7;
        float xv_p[8] = {0,0,0,0,0,0,0,0};
        float an_p[8] = {0,0,0,0,0,0,0,0};
        #pragma unroll
        for (int i = 0; i < 2; ++i) {
            int e = (eq * 2 + i) * 16 + ec;
            short8 v = *(const short8*)((char*)tbuf + (l_loc * 2048 + e * 16));
            float w2 = W2[e], w4 = W4[128 + e];
            #pragma unroll
            for (int h = 0; h < 8; ++h) {
                float gv = gelu_f(bf2f(v[h]));
                xv_p[h] += gv * w2;
                an_p[h] += gv * w4;
            }
        }
        #pragma unroll
        for (int h = 0; h < 8; ++h) {
            #pragma unroll
            for (int m = 1; m < 16; m <<= 1) {
                xv_p[h] += __shfl_xor(xv_p[h], m);
                an_p[h] += __shfl_xor(an_p[h], m);
            }
        }
        if (ec == 0) {
            #pragma unroll
            for (int h = 0; h < 8; ++h) {
                rs4[eq][l_loc * 8 + h][0] = xv_p[h];
                rs4[eq][l_loc * 8 + h][1] = an_p[h];
            }
        }
    }

    // Phase D: tbuf -> xhb k-packed; one kg per block
    int n = b >> 6, kg = b & 63;
    #pragma unroll
    for (int rep = 0; rep < 2; ++rep) {
        int id = rep * 512 + tid;
        int h = id >> 7, e = id & 127;
        short8 v;
        #pragma unroll
        for (int j = 0; j < 8; ++j)
            v[j] = (short)*(const unsigned short*)((char*)tbuf + (j * 2048 + e * 16 + h * 2));
        *(short8*)(xhb + ((size_t)(n * 8 + h)) * 65536 + (size_t)(kg * 128 + e) * 8) = v;
    }
    __syncthreads();

    if (tid < 64) {
        rs[tid][0] = rs4[0][tid][0] + rs4[1][tid][0] + rs4[2][tid][0] + rs4[3][tid][0];
        rs[tid][1] = rs4[0][tid][1] + rs4[1][tid][1] + rs4[2][tid][1] + rs4[3][tid][1];
    }
    __syncthreads();
    if (tid < 8) {
        int l = kg * 8 + tid;
        float xv[8], an[8];
        #pragma unroll
        for (int h = 0; h < 8; ++h) { xv[h] = rs[tid * 8 + h][0]; an[h] = rs[tid * 8 + h][1]; }
        float mx = xv[0];
        #pragma unroll
        for (int h = 1; h < 8; ++h) mx = fmaxf(mx, xv[h]);
        float ex[8], ssum = 0.f;
        #pragma unroll
        for (int h = 0; h < 8; ++h) { ex[h] = expf(xv[h] - mx); ssum += ex[h]; }
        float inv = 1.0f / ssum;
        #pragma unroll
        for (int h = 0; h < 8; ++h)
            sb[((size_t)(n * 8 + h)) * 512 + l] = bf16_rne(ex[h] * inv);
        float mxa = an[0];
        #pragma unroll
        for (int h = 1; h < 8; ++h) mxa = fmaxf(mxa, an[h]);
        f32x4 e0, e1;
        #pragma unroll
        for (int h = 0; h < 4; ++h) e0[h] = expf(an[h] - mxa);
        #pragma unroll
        for (int h = 0; h < 4; ++h) e1[h] = expf(an[4 + h] - mxa);
        float* ep = eu + ((size_t)(n * 512 + l)) * 8;
        *(f32x4*)ep = e0;
        *(f32x4*)(ep + 4) = e1;
    }
}

// ---------------- k23_fused: stage1 heg = gelu(A'@xh) (LDS bf16) ; stage2 he = heg@W3+b3
__global__ __launch_bounds__(1024) void k23_fused(const unsigned short* __restrict__ xhb,
                                                  const unsigned short* __restrict__ s_in,
                                                  const unsigned* __restrict__ bitsT,
                                                  const unsigned short* __restrict__ W3h,
                                                  const float* __restrict__ b3,
                                                  const float* __restrict__ W4,
                                                  unsigned short* __restrict__ heT,
                                                  float* __restrict__ ev) {
    __shared__ __align__(16) unsigned short kpk[65536];    // 128 KB; after stage1: A2 (64KB) | tbuf (64KB)
    __shared__ unsigned bT_s[16 * 256];                    // 16 KB
    __shared__ __align__(16) unsigned short smb_s[512];    // 1 KB
    __shared__ float rs_ae[256][2];                        // 2 KB
    int bh = blockIdx.x;
    int n = bh >> 3, h = bh & 7;
    int tid = threadIdx.x, lane = tid & 63, w = tid >> 6;
    int rl = lane & 15, g = lane >> 4;

    {
        int p = tid >> 2, q = tid & 3;
        uint4 wds = *(const uint4*)(bitsT + ((size_t)(n * 256 + p)) * 16 + q * 4);
        bT_s[(q * 4 + 0) * 256 + p] = wds.x;
        bT_s[(q * 4 + 1) * 256 + p] = wds.y;
        bT_s[(q * 4 + 2) * 256 + p] = wds.z;
        bT_s[(q * 4 + 3) * 256 + p] = wds.w;
    }
    if (tid < 512) smb_s[tid] = s_in[(size_t)bh * 512 + tid];
    {
        const unsigned short* xb = xhb + (size_t)bh * 65536;
        #pragma unroll
        for (int rep = 0; rep < 8; ++rep) {
            int idx = rep * 1024 + tid;
            *(short8*)&kpk[idx * 8] = *(const short8*)(xb + (size_t)idx * 8);
        }
    }
    __syncthreads();

    // ---- stage 1: heg[p][e] = A' @ xh (acc in regs)
    int wm = w & 7, wn = w >> 3;
    f32x4 acc[2][4];
    #pragma unroll
    for (int i = 0; i < 2; ++i)
        #pragma unroll
        for (int nt = 0; nt < 4; ++nt) acc[i][nt] = (f32x4){0.f, 0.f, 0.f, 0.f};

    for (int kt = 0; kt < 16; ++kt) {
        short8 sv = *(const short8*)&smb_s[kt * 32 + g * 8];
        short8 bfr[4];
        #pragma unroll
        for (int nt = 0; nt < 4; ++nt)
            bfr[nt] = *(const short8*)&kpk[(((kt * 4 + g) << 7) + wn * 64 + nt * 16 + rl) * 8];
        #pragma unroll
        for (int i = 0; i < 2; ++i) {
            unsigned word = bT_s[kt * 256 + (wm * 2 + i) * 16 + rl];
            unsigned byte = (word >> (g * 8)) & 255u;
            short8 af;
            #pragma unroll
            for (int j = 0; j < 8; ++j)
                af[j] = ((byte >> j) & 1u) ? sv[j] : (short)0x3E00;
            #pragma unroll
            for (int nt = 0; nt < 4; ++nt)
                acc[i][nt] = __builtin_amdgcn_mfma_f32_16x16x32_bf16(af, bfr[nt], acc[i][nt], 0, 0, 0);
        }
    }
    __syncthreads();   // all waves done reading kpk; reuse as A2 | tbuf

    char* A2  = (char*)kpk;           // A2[p][e] bf16, row 256B, swz ^((p&15)<<4)
    char* tb2 = (char*)kpk + 65536;   // tbuf he[f][p] bf16, row 512B, swz ^((f&7)<<4)

    #pragma unroll
    for (int i = 0; i < 2; ++i)
        #pragma unroll
        for (int nt = 0; nt < 4; ++nt) {
            int e = wn * 64 + nt * 16 + rl;
            #pragma unroll
            for (int r = 0; r < 4; ++r) {
                int p = (wm * 2 + i) * 16 + g * 4 + r;
                *(unsigned short*)(A2 + ((p * 256 + e * 2) ^ ((p & 15) << 4))) =
                    bf16_rne(gelu_f(acc[i][nt][r]));
            }
        }
    __syncthreads();

    // ---- stage 2: he[p][f] = A2 @ W3h + b3
    f32x4 acc2[2][4];
    #pragma unroll
    for (int i = 0; i < 2; ++i)
        #pragma unroll
        for (int nt = 0; nt < 4; ++nt) acc2[i][nt] = (f32x4){0.f, 0.f, 0.f, 0.f};

    #pragma unroll
    for (int kt2 = 0; kt2 < 4; ++kt2) {
        short8 af2[2];
        #pragma unroll
        for (int i = 0; i < 2; ++i) {
            int p = (wm * 2 + i) * 16 + rl;
            af2[i] = *(const short8*)(A2 + ((p * 256 + (kt2 * 32 + g * 8) * 2) ^ ((p & 15) << 4)));
        }
        #pragma unroll
        for (int nt = 0; nt < 4; ++nt) {
            int oct = kt2 * 4 + g, col = (wn * 4 + nt) * 16 + rl;
            short8 bhv = *(const short8*)(W3h + ((size_t)(oct * 128 + col)) * 8);
            #pragma unroll
            for (int i = 0; i < 2; ++i)
                acc2[i][nt] = __builtin_amdgcn_mfma_f32_16x16x32_bf16(af2[i], bhv, acc2[i][nt], 0, 0, 0);
        }
    }

    // ---- epilogue: bias, ae partials, he -> tbuf (transposed)
    float ae_p[2][4] = {{0.f,0.f,0.f,0.f},{0.f,0.f,0.f,0.f}};
    #pragma unroll
    for (int nt = 0; nt < 4; ++nt) {
        int f = (wn * 4 + nt) * 16 + rl;
        float bv = b3[f], w4v = W4[f];
        #pragma unroll
        for (int i = 0; i < 2; ++i) {
            float v0 = acc2[i][nt][0] + bv;
            float v1 = acc2[i][nt][1] + bv;
            float v2 = acc2[i][nt][2] + bv;
            float v3 = acc2[i][nt][3] + bv;
            ae_p[i][0] += gelu_f(v0) * w4v;
            ae_p[i][1] += gelu_f(v1) * w4v;
            ae_p[i][2] += gelu_f(v2) * w4v;
            ae_p[i][3] += gelu_f(v3) * w4v;
            int p0 = (wm * 2 + i) * 16 + g * 4;
            int byte = (f * 512 + p0 * 2) ^ ((f & 7) << 4);
            *(ushort4*)(tb2 + byte) =
                make_ushort4(bf16_rne(v0), bf16_rne(v1), bf16_rne(v2), bf16_rne(v3));
        }
    }
    #pragma unroll
    for (int i = 0; i < 2; ++i)
        #pragma unroll
        for (int r = 0; r < 4; ++r) {
            float a = ae_p[i][r];
            a += __shfl_xor(a, 1); a += __shfl_xor(a, 2); a += __shfl_xor(a, 4); a += __shfl_xor(a, 8);
            if (rl == 0) rs_ae[(wm * 2 + i) * 16 + g * 4 + r][wn] = a;
        }
    __syncthreads();

    unsigned short* ho = heT + (size_t)bh * 32768;
    #pragma unroll
    for (int rep = 0; rep < 4; ++rep) {
        int id = rep * 1024 + tid;
        int f = id >> 5, pj = id & 31;
        int byte = (f * 512 + pj * 16) ^ ((f & 7) << 4);
        short8 v = *(const short8*)(tb2 + byte);
        *(short8*)(ho + (size_t)f * 256 + pj * 8) = v;
    }
    if (tid < 256) {
        float ae = rs_ae[tid][0] + rs_ae[tid][1];
        ev[((size_t)(n * 256 + tid)) * 8 + h] = expf(ae);
    }
}

// ---------------- k4_dense: rdm[n][l][p] = bit ? 1/den : 0  (bf16, h-shared)
__global__ __launch_bounds__(256) void k4_dense(const float* __restrict__ eu,
                                                const float* __restrict__ ev,
                                                const unsigned* __restrict__ bits,
                                                unsigned short* __restrict__ rdm) {
    __shared__ float ev_t[256][8];
    int b = blockIdx.x;
    int n = b >> 3, l0 = (b & 7) * 64;
    int tid = threadIdx.x;
    {
        const f32x4* src = (const f32x4*)(ev + (size_t)n * 2048);
        f32x4* dst = (f32x4*)&ev_t[0][0];
        dst[tid] = src[tid];
        dst[tid + 256] = src[tid + 256];
    }
    __syncthreads();
    int l = l0 + (tid >> 2), pq = tid & 3;
    size_t rowg = (size_t)n * 512 + l;
    f32x4 ea = *(const f32x4*)(eu + rowg * 8);
    f32x4 eb = *(const f32x4*)(eu + rowg * 8 + 4);
    unsigned w0 = bits[rowg * 8 + pq * 2], w1 = bits[rowg * 8 + pq * 2 + 1];
    for (int c = 0; c < 8; ++c) {
        short8 o8;
        #pragma unroll
        for (int k = 0; k < 8; ++k) {
            int pl = c * 8 + k;
            int p = pq * 64 + pl;
            f32x4 va = *(const f32x4*)&ev_t[p][0];
            f32x4 vb = *(const f32x4*)&ev_t[p][4];
            float den = ea.x * va.x + ea.y * va.y + ea.z * va.z + ea.w * va.w
                      + eb.x * vb.x + eb.y * vb.y + eb.z * vb.z + eb.w * vb.w;
            unsigned bit = (pl < 32) ? ((w0 >> pl) & 1u) : ((w1 >> (pl - 32)) & 1u);
            float r = bit ? rcp_f(den) : 0.0f;
            o8[k] = (short)bf16_rne(r);
        }
        *(short8*)(rdm + rowg * 256 + pq * 64 + c * 8) = o8;
    }
}

// ---------------- k5_mfma: x_nodes = 0.125*colsum(he) + A @ he; 1024 threads (16 waves)
__global__ __launch_bounds__(1024) void k5_mfma(const unsigned short* __restrict__ heT,
                                                const unsigned short* __restrict__ rdm,
                                                const float* __restrict__ eu,
                                                const float* __restrict__ ev,
                                                const unsigned* __restrict__ flags,
                                                const float* __restrict__ x,
                                                float* __restrict__ out) {
    __shared__ __align__(16) unsigned short heT_s[128 * 256];  // swizzled [e][p], 64 KB
    __shared__ __align__(16) unsigned short A_s[64 * 256];     // swizzled [l_loc][p], 32 KB
    __shared__ float evh_s[256];
    __shared__ float euh_s[64];
    __shared__ float cs_s[128];
    __shared__ float csr_s[4][128];
    __shared__ unsigned flg_s[64];

    int bid = blockIdx.x;
    int xcd = bid & 7, slot = bid >> 3;
    int n = xcd * 4 + (slot & 3), h = slot >> 2;
    int bh = n * 8 + h;
    int tid = threadIdx.x, lane = tid & 63, w = tid >> 6;

    const unsigned short* hb = heT + (size_t)bh * 32768;
    #pragma unroll
    for (int i = 0; i < 4; ++i) {
        int id = tid + i * 1024;
        int e = id >> 5, jj = id & 31;
        short8 v = *(const short8*)(hb + e * 256 + jj * 8);
        *(short8*)((char*)heT_s + ((e * 512 + jj * 16) ^ ((e & 7) << 4))) = v;
    }
    if (tid < 256) evh_s[tid] = ev[((size_t)(n * 256 + tid)) * 8 + h];
    __syncthreads();
    if (tid < 512) {
        int e = tid & 127, q = tid >> 7;
        float a = 0.f;
        #pragma unroll
        for (int j = 0; j < 8; ++j) {
            int byte = (e * 512 + (q * 64 + j * 8) * 2) ^ ((e & 7) << 4);
            short8 v = *(const short8*)((char*)heT_s + byte);
            #pragma unroll
            for (int k = 0; k < 8; ++k) a += bf2f(v[k]);
        }
        csr_s[q][e] = a;
    }
    __syncthreads();
    if (tid < 128) cs_s[tid] = 0.125f * (csr_s[0][tid] + csr_s[1][tid] + csr_s[2][tid] + csr_s[3][tid]);

    int rl = lane & 15, g = lane >> 4;
    int wm = w & 3, wn = w >> 2;
    int swz = (rl & 7) << 4;

    for (int lt = 0; lt < 8; ++lt) {
        int l0 = lt * 64;
        if (tid < 64) {
            euh_s[tid] = eu[((size_t)(n * 512 + l0 + tid)) * 8 + h];
            flg_s[tid] = flags[n * 512 + l0 + tid];
        }
        __syncthreads();
        {
            int l_loc = tid >> 4, p8 = (tid & 15) * 16;
            float euh = euh_s[l_loc];
            const unsigned short* rp = rdm + ((size_t)(n * 512 + l0 + l_loc)) * 256 + p8;
            #pragma unroll
            for (int c = 0; c < 2; ++c) {
                short8 rv = *(const short8*)(rp + c * 8);
                short8 o8;
                #pragma unroll
                for (int k = 0; k < 8; ++k) {
                    unsigned u = (unsigned)(unsigned short)rv[k];
                    float rf = __uint_as_float(u << 16);
                    float m125 = (u != 0u) ? -0.125f : 0.0f;
                    float a = fmaf(euh * evh_s[p8 + c * 8 + k], rf, m125);
                    o8[k] = (short)bf16_rne(a);
                }
                *(short8*)((char*)A_s + ((l_loc * 512 + (p8 + c * 8) * 2) ^ ((l_loc & 7) << 4))) = o8;
            }
        }
        __syncthreads();
        f32x4 acc[2];
        acc[0] = (f32x4){0.f, 0.f, 0.f, 0.f};
        acc[1] = (f32x4){0.f, 0.f, 0.f, 0.f};
        #pragma unroll
        for (int kt = 0; kt < 8; ++kt) {
            int arow = wm * 16 + rl;
            short8 af = *(const short8*)((char*)A_s + ((arow * 512 + kt * 64 + g * 16) ^ swz));
            short8 b0, b1;
            {
                int e0 = wn * 32 + rl;
                int e1 = wn * 32 + 16 + rl;
                b0 = *(const short8*)((char*)heT_s + ((e0 * 512 + kt * 64 + g * 16) ^ swz));
                b1 = *(const short8*)((char*)heT_s + ((e1 * 512 + kt * 64 + g * 16) ^ swz));
            }
            acc[0] = __builtin_amdgcn_mfma_f32_16x16x32_bf16(af, b0, acc[0], 0, 0, 0);
            acc[1] = __builtin_amdgcn_mfma_f32_16x16x32_bf16(af, b1, acc[1], 0, 0, 0);
        }
        #pragma unroll
        for (int j = 0; j < 2; ++j) {
            int e = wn * 32 + j * 16 + rl;
            float csv = cs_s[e];
            #pragma unroll
            for (int r = 0; r < 4; ++r) {
                int row = wm * 16 + g * 4 + r;
                int l = l0 + row;
                size_t addr = ((size_t)(n * 512 + l)) * 1024 + h * 128 + e;
                if (flg_s[row]) {
                    out[addr] = x[addr];
                } else {
                    out[addr] = gelu_f(acc[j][r] + csv);
                }
            }
        }
        __syncthreads();
    }
}

extern "C" void kernel_launch(void* const* d_in, const int* in_sizes, int n_in,
                              void* d_out, int out_size, void* d_ws, size_t ws_size,
                              hipStream_t stream) {
    (void)in_sizes; (void)n_in; (void)out_size; (void)ws_size;
    const float* x   = (const float*)d_in[0];
    const float* adj = (const float*)d_in[1];
    const float* W1  = (const float*)d_in[2];
    const float* b1  = (const float*)d_in[3];
    const float* W2  = (const float*)d_in[4];
    const float* W3  = (const float*)d_in[6];
    const float* b3  = (const float*)d_in[7];
    const float* W4  = (const float*)d_in[8];
    float* out = (float*)d_out;

    char* ws = (char*)d_ws;
    size_t off = 0;
    auto alloc = [&](size_t bytes) -> void* {
        void* p = ws + off;
        off += (bytes + 255) & ~(size_t)255;
        return p;
    };
    unsigned short* xhb = (unsigned short*)alloc((size_t)NB * HH * 65536 * 2);   // 33.5 MB bf16 k-packed
    unsigned short* sb  = (unsigned short*)alloc((size_t)NB * HH * LL * 2);      // bf16 s
    float* eu   = (float*)alloc((size_t)NB * LL * HH * 4);
    float* ev   = (float*)alloc((size_t)NB * PP * HH * 4);
    unsigned short* heT = (unsigned short*)alloc((size_t)NB * HH * EE * PP * 2); // 16.8 MB [(n,h)][f][p]
    unsigned short* rdm = (unsigned short*)alloc((size_t)NB * LL * PP * 2);      // 8.4 MB [n][l][p]
    unsigned* bits  = (unsigned*)alloc((size_t)NB * LL * 8 * 4);
    unsigned* bitsT = (unsigned*)alloc((size_t)NB * PP * 16 * 4);
    unsigned* flags = (unsigned*)alloc((size_t)NB * LL * 4);
    unsigned short* W1h = (unsigned short*)alloc(16384 * 2);
    unsigned short* W1l = (unsigned short*)alloc(16384 * 2);
    unsigned short* W3h = (unsigned short*)alloc(16384 * 2);
    unsigned short* W3l = (unsigned short*)alloc(16384 * 2);

    hipLaunchKernelGGL(kpack, dim3(2), dim3(256), 0, stream, W1, W3, W1h, W1l, W3h, W3l);
    hipLaunchKernelGGL(k0_bits, dim3(NB * 8), dim3(256), 0, stream, adj, bits, bitsT, flags);
    hipLaunchKernelGGL(gemm1c, dim3(2048), dim3(512), 0, stream, x, W1h, b1, W2, W4, xhb, sb, eu);
    hipLaunchKernelGGL(k23_fused, dim3(NB * HH), dim3(1024), 0, stream, xhb, sb, bitsT, W3h, b3, W4, heT, ev);
    hipLaunchKernelGGL(k4_dense, dim3(NB * 8), dim3(256), 0, stream, eu, ev, bits, rdm);
    hipLaunchKernelGGL(k5_mfma, dim3(NB * HH), dim3(1024), 0, stream, heT, rdm, eu, ev, flags, x, out);
}